// Round 10
// baseline (241.958 us; speedup 1.0000x reference)
//
#include <hip/hip_runtime.h>

#define NS 128
#define NP 32
#define HD 32
#define ED 16
#define GH 72
#define GO 8
#define MD 64
#define TT 8
#define NB (NS*NP)
#define EW 76

#define SLOT 272   // floats per slot: 256 data + flag + pad
// 256 blocks x 2 parity slots
#define WS_NEED (256*2*SLOT*4)

typedef float v2f __attribute__((ext_vector_type(2)));

__device__ __forceinline__ float sigm(float x){ return 1.0f/(1.0f+__expf(-x)); }
__device__ __forceinline__ float tanhfast(float x){ return 1.0f - 2.0f/(__expf(2.0f*x)+1.0f); }
__device__ __forceinline__ unsigned rne16(float f){
  unsigned u = __float_as_uint(f);
  u += 0x7fffu + ((u>>16)&1u);
  return u>>16;
}
__device__ __forceinline__ float lo16(unsigned v){ return __uint_as_float(v<<16); }
__device__ __forceinline__ float hi16(unsigned v){ return __uint_as_float(v & 0xffff0000u); }
// wave-uniform broadcast from lane l (VALU pipe, not DS)
__device__ __forceinline__ float rdlane(float v, int l){
  return __int_as_float(__builtin_amdgcn_readlane(__float_as_int(v), l));
}
// DPP cross-lane move (VALU pipe).
// 0xB1 = quad_perm xor1, 0x4E = quad_perm xor2,
// 0x141 = row_half_mirror (8-sum after xor1/xor2), 0x140 = row_mirror (16-sum).
template<int C>
__device__ __forceinline__ float dppx(float x){
  return __int_as_float(__builtin_amdgcn_update_dpp(0, __float_as_int(x), C, 0xF, 0xF, true));
}
#define XOR1 0xB1
#define XOR2 0x4E
#define HMIR 0x141
#define MIR  0x140
// full 32-lane sum: 4 DPP levels + one DS shfl for the 16-offset
__device__ __forceinline__ float wsum32(float v){
  v += dppx<XOR1>(v);
  v += dppx<XOR2>(v);
  v += dppx<HMIR>(v);
  v += dppx<MIR >(v);
  v += __shfl_xor(v, 16, 32);
  return v;
}

// ==================== split kernel: 256 blocks, (scene, m) per block ====================
__global__ __launch_bounds__(1024, 1) void decoder_kernel_split(
    const float* __restrict__ last_pos, const float* __restrict__ last_pos_rel,
    const float* __restrict__ hh, const float* __restrict__ ch,
    const int*  __restrict__ eg,
    const float* __restrict__ W_se, const float* __restrict__ b_se,
    const float* __restrict__ Wih, const float* __restrict__ Whh,
    const float* __restrict__ bih, const float* __restrict__ bhh,
    const float* __restrict__ W_hp, const float* __restrict__ b_hp,
    const float* __restrict__ W_pse, const float* __restrict__ b_pse,
    const float* __restrict__ W1a, const float* __restrict__ W2a,
    const float* __restrict__ W1b, const float* __restrict__ W2b,
    const float* __restrict__ W_m1, const float* __restrict__ b_m1,
    const float* __restrict__ W_m2, const float* __restrict__ b_m2,
    float* __restrict__ out, float* __restrict__ ws)
{
  const int tid   = threadIdx.x;
  const int scn   = blockIdx.x >> 1;
  const int myM   = blockIdx.x & 1;
  const int lane  = tid & 31;
  const int grp32 = tid >> 5;      // 0..31

  // uni overlays: G[32][128] gate staging (16 KB) <-> a1[32][76] (9.7 KB) <-> m1-stage (P4, uni+2048)
  __shared__ __align__(16) float uni[4096];
  __shared__ __align__(16) unsigned W1pT[GH][16];  // own m, bf16 pairs, TRANSPOSED (row d = 16 dwords)
  __shared__ __align__(16) float Wp1[2][GH];       // own m
  __shared__ __align__(16) float c1l[GH];          // own m
  __shared__ __align__(16) float ebuf[NP*EW];      // e[i][d] = c1 - lp[i].Wp1  (P3 coef precompute)
  __shared__ __align__(16) float hbuf[NP][HD];
  __shared__ __align__(16) float h2buf[NP][36];
  __shared__ __align__(16) float GS[5][GH];        // own m
  __shared__ __align__(16) float phbuf[NP][16];
  __shared__ __align__(16) unsigned Wm1p[48][32];
  __shared__ __align__(16) unsigned Wm2p[32][32];
  __shared__ float lpbuf[NP][2], rpbuf[NP][2], Whp[HD][2];
  __shared__ float bm1l[MD], bm2l[HD], bhp2[2];
  __shared__ unsigned bm[NP];
  __shared__ unsigned gmsk[5];                     // group membership masks (g=0 -> all)
  __shared__ float invn[NP];
  __shared__ int gl[NP];

  float* const a1 = uni;   // [32][76]

  const int mybase = (scn*2 + myM)*2;       // slot-pair index (x SLOT)
  const int pbase  = (scn*2 + 1 - myM)*2;

  // ---------- persistent per-thread LSTM row weights (global read ONCE) ----------
  const int myrow = tid & 127;
  const int pq4   = tid >> 7;
  float wrow[HD];
  #pragma unroll
  for (int c = 0; c < HD/4; c++) {
    float4 w = *(const float4*)(Whh + myrow*HD + c*4);
    wrow[c*4+0]=w.x; wrow[c*4+1]=w.y; wrow[c*4+2]=w.z; wrow[c*4+3]=w.w;
  }
  float wf0 = 0.f, wf1 = 0.f, bfr = bih[myrow] + bhh[myrow];
  #pragma unroll
  for (int e = 0; e < ED; e++) {
    float wv = Wih[myrow*ED + e];
    wf0 = fmaf(W_se[e],    wv, wf0);
    wf1 = fmaf(W_se[ED+e], wv, wf1);
    bfr = fmaf(b_se[e],    wv, bfr);
  }

  float creg = ch[(scn*NP + grp32)*HD + lane];
  hbuf[grp32][lane] = hh[(scn*NP + grp32)*HD + lane];

  // ---------- setup ----------
  if (tid < NP) {
    int gi = eg[scn*NP + tid];
    gl[tid] = gi;
    unsigned sm = 0;
    for (int j = 0; j < NP; j++) {
      int gj = eg[scn*NP + j];
      bool sj = (j == tid) || (gi == gj && gi != 0);
      sm |= ((unsigned)sj) << j;
    }
    unsigned mk = myM ? ((~sm) | (1u << tid)) : sm;
    bm[tid] = mk;
    invn[tid] = 1.0f/(float)__popc(mk);
  }
  if (tid < 5) {       // membership mask per group id
    unsigned mv = 0;
    for (int j = 0; j < NP; j++) if (eg[scn*NP + j] == tid) mv |= (1u << j);
    gmsk[tid] = (tid == 0) ? 0xFFFFFFFFu : mv;
  }
  if (tid < 64) {
    int p = tid >> 1, k = tid & 1;
    lpbuf[p][k] = last_pos[(scn*NP+p)*2+k];
    rpbuf[p][k] = last_pos_rel[(scn*NP+p)*2+k];
    Whp[p][k]   = W_hp[tid];
    bm1l[tid]   = b_m1[tid];
  }
  if (tid < 32) bm2l[tid] = b_m2[tid];
  if (tid < 2)  bhp2[tid] = b_hp[tid];
  const float* W1my = myM ? W1b : W1a;
  const float* W2g  = myM ? W2b : W2a;    // W2 read from GLOBAL with uniform index -> s_load, off the DS pipe
  if (tid < GH) {   // folded Wp1 = W_pse@W1[:16], c1 = b_pse@W1[:16] (own m)
    int d = tid;
    float s0 = 0.f, s1 = 0.f, sc1 = 0.f;
    for (int e = 0; e < ED; e++) {
      float w = W1my[e*GH + d];
      s0  += W_pse[e]    * w;
      s1  += W_pse[ED+e] * w;
      sc1 += b_pse[e]    * w;
    }
    Wp1[0][d] = s0; Wp1[1][d] = s1; c1l[d] = sc1;
  }
  #pragma unroll
  for (int r = 0; r < 2; r++) {  // W1pT own m, packed bf16, transposed (1152 > 1024: TWO passes)
    int u = tid + 1024*r;
    if (u < 16*GH) {
      int k2 = u/GH, d = u%GH;
      unsigned lo = rne16(W1my[(ED+2*k2  )*GH + d]);
      unsigned hi = rne16(W1my[(ED+2*k2+1)*GH + d]);
      W1pT[d][k2] = lo | (hi << 16);
    }
  }
  #pragma unroll
  for (int r = 0; r < 2; r++) {   // Wm1p packed bf16 (1536)
    int u = tid + 1024*r;
    if (u < 1536) {
      int k = u >> 5, uu = u & 31;
      Wm1p[k][uu] = rne16(W_m1[k*MD + uu]) | (rne16(W_m1[k*MD + 32 + uu]) << 16);
    }
  }
  {  // Wm2p packed bf16 (1024)
    int k = tid >> 5, uu = tid & 31;
    Wm2p[k][uu] = rne16(W_m2[k*HD + uu]) | (rne16(W_m2[(k+32)*HD + uu]) << 16);
  }
  __syncthreads();

  // ---------------- time steps ----------------
  for (int t = 0; t < TT; t++) {
    // P1a: gates[p][myrow] for 4 peds (redundant in both blocks; deterministic)
    {
      float hv[4];
      #pragma unroll
      for (int pp2 = 0; pp2 < 4; pp2++) hv[pp2] = hbuf[pq4*4 + pp2][lane];
      float rG[4];
      #pragma unroll
      for (int pp2 = 0; pp2 < 4; pp2++) {
        int p = pq4*4 + pp2;
        float acc = fmaf(rpbuf[p][0], wf0, fmaf(rpbuf[p][1], wf1, bfr));
        #pragma unroll
        for (int c = 0; c < HD; c++)
          acc = fmaf(rdlane(hv[pp2], c), wrow[c], acc);
        rG[pp2] = acc;
      }
      #pragma unroll
      for (int pp2 = 0; pp2 < 4; pp2++) uni[(pq4*4+pp2)*128 + myrow] = rG[pp2];
    }
    __syncthreads();

    // P1b: activations, c/h2 update; rel_pos reduction; out store (m=0 block only)
    {
      int p = grp32, n = lane;
      float gi_ = uni[p*128 +       n];
      float gf_ = uni[p*128 +  32 + n];
      float gg_ = uni[p*128 +  64 + n];
      float go_ = uni[p*128 +  96 + n];
      float c2 = sigm(gf_)*creg + sigm(gi_)*tanhfast(gg_);
      creg = c2;
      float h2 = sigm(go_)*tanhfast(c2);
      h2buf[p][n] = h2;
      float r0 = h2 * Whp[n][0];
      float r1 = h2 * Whp[n][1];
      // full reduction tree on VALU via DPP, one DS shfl for the 16-offset
      r0 += dppx<XOR1>(r0); r1 += dppx<XOR1>(r1);
      r0 += dppx<XOR2>(r0); r1 += dppx<XOR2>(r1);
      r0 += dppx<HMIR>(r0); r1 += dppx<HMIR>(r1);
      r0 += dppx<MIR >(r0); r1 += dppx<MIR >(r1);
      r0 += __shfl_xor(r0, 16, 32);
      r1 += __shfl_xor(r1, 16, 32);
      r0 += bhp2[0]; r1 += bhp2[1];
      if (n == 0) {
        if (myM == 0) {
          out[t*NB*2 + (scn*NP+p)*2 + 0] = r0;
          out[t*NB*2 + (scn*NP+p)*2 + 1] = r1;
        }
        rpbuf[p][0] = r0;  rpbuf[p][1] = r1;
        lpbuf[p][0] += r0; lpbuf[p][1] += r1;
      }
    }
    __syncthreads();

    // P2: a1[j][d] + GS group sums via DPP trees (R14: P2b phase + barrier deleted) + ebuf precompute
    {
      const int j = lane;
      float lpj0 = lpbuf[j][0], lpj1 = lpbuf[j][1];
      const int gj = gl[j];
      float h2row[HD];
      #pragma unroll
      for (int c = 0; c < 8; c++) {
        float4 v = *(const float4*)&h2buf[j][c*4];
        h2row[c*4+0]=v.x; h2row[c*4+1]=v.y; h2row[c*4+2]=v.z; h2row[c*4+3]=v.w;
      }
      #pragma unroll
      for (int r = 0; r < 3; r++) {
        int d = grp32 + 32*r;
        if (d < GH) {
          float av = fmaf(lpj0, Wp1[0][d], lpj1*Wp1[1][d]);
          #pragma unroll
          for (int k8 = 0; k8 < 4; k8++) {   // 4 half-wave-uniform b128
            uint4 w4 = *(const uint4*)&W1pT[d][k8*4];
            av = fmaf(h2row[k8*8+0], lo16(w4.x), av);
            av = fmaf(h2row[k8*8+1], hi16(w4.x), av);
            av = fmaf(h2row[k8*8+2], lo16(w4.y), av);
            av = fmaf(h2row[k8*8+3], hi16(w4.y), av);
            av = fmaf(h2row[k8*8+4], lo16(w4.z), av);
            av = fmaf(h2row[k8*8+5], hi16(w4.z), av);
            av = fmaf(h2row[k8*8+6], lo16(w4.w), av);
            av = fmaf(h2row[k8*8+7], hi16(w4.w), av);
          }
          a1[j*EW + d] = av;
          // R14: GS via DPP trees (VALU), replacing the separate P2b phase
          float tot = wsum32(av);
          float s1 = wsum32((gj==1) ? av : 0.f);
          float s2 = wsum32((gj==2) ? av : 0.f);
          float s3 = wsum32((gj==3) ? av : 0.f);
          float s4 = wsum32((gj==4) ? av : 0.f);
          if (j < 5) {
            float v2;
            if (myM == 0) v2 = (j==0)?tot:((j==1)?s1:((j==2)?s2:((j==3)?s3:s4)));
            else          v2 = (j==0)?tot:((j==1)?tot-s1:((j==2)?tot-s2:((j==3)?tot-s3:tot-s4)));
            GS[j][d] = v2;
          }
        }
      }
      // e[i][d] precompute
      #pragma unroll
      for (int ii = 0; ii < 3; ii++) {
        int idx = tid + 1024*ii;
        if (idx < NP*GH) {
          int d = idx >> 5, i2 = idx & 31;
          ebuf[i2*EW + d] = fmaf(-lpbuf[i2][1], Wp1[1][d],
                            fmaf(-lpbuf[i2][0], Wp1[0][d], c1l[d]));
        }
      }
    }
    __syncthreads();

    // P3: pool (own m). One task per thread: i = grp32, j = lane.
    // Unroll-by-2 for ILP + packed-fp32 tv.
    {
      const int j = lane, i = grp32;
      unsigned bmv = bm[i];
      bool mij = (bmv >> j) & 1u;
      bool diag = (j == i);
      int gi = gl[i];
      float in_ = invn[i];
      const float *p0, *p1; float c0, c1c;
      if (diag) {
        if (myM == 0) { p0 = gi ? &GS[gi][0] : (a1 + i*EW); c0 = in_; p1 = a1 + i*EW; c1c = 0.f; }
        else          { p0 = &GS[gi][0];                    c0 = in_; p1 = a1 + i*EW; c1c = gi ? in_ : 0.f; }
      } else if (mij) { p0 = a1 + j*EW; c0 = 0.5f; p1 = a1 + i*EW; c1c = 0.5f; }
      else            { p0 = a1 + j*EW; c0 = 1.0f; p1 = a1 + j*EW; c1c = 0.f; }
      const float* erow = ebuf + i*EW;
      const v2f c0v = (v2f){c0, c0};
      const v2f c1v = (v2f){c1c, c1c};
      v2f qv[4];
      #pragma unroll
      for (int h = 0; h < 4; h++) qv[h] = (v2f){0.f, 0.f};
      #pragma unroll 2
      for (int d4 = 0; d4 < GH/4; d4++) {
        float4 e4 = *(const float4*)(erow + d4*4);
        float4 va = diag ? *(const float4*)(p0 + d4*4)
                         : *(const float4*)(a1 + j*EW + d4*4);
        float4 vb = *(const float4*)(p1 + d4*4);
        // packed tv: t = relu(c0*va + (c1c*vb + e)) on v_pk_fma_f32/v_pk_max_f32
        v2f e01 = (v2f){e4.x, e4.y}, e23 = (v2f){e4.z, e4.w};
        v2f va01 = (v2f){va.x, va.y}, va23 = (v2f){va.z, va.w};
        v2f vb01 = (v2f){vb.x, vb.y}, vb23 = (v2f){vb.z, vb.w};
        v2f u01 = c1v*vb01 + e01;
        v2f u23 = c1v*vb23 + e23;
        v2f t01 = c0v*va01 + u01;
        v2f t23 = c0v*va23 + u23;
        t01 = (v2f){fmaxf(t01[0], 0.f), fmaxf(t01[1], 0.f)};
        t23 = (v2f){fmaxf(t23[0], 0.f), fmaxf(t23[1], 0.f)};
        float tv[4] = {t01[0], t01[1], t23[0], t23[1]};
        #pragma unroll
        for (int k = 0; k < 4; k++) {
          // uniform global reads -> s_load into SGPRs, zero DS traffic
          const float* wr = W2g + (d4*4+k)*GO;
          v2f wA = {wr[0], wr[1]}, wB = {wr[2], wr[3]};
          v2f wC = {wr[4], wr[5]}, wD = {wr[6], wr[7]};
          v2f tk = {tv[k], tv[k]};
          qv[0] += tk*wA; qv[1] += tk*wB; qv[2] += tk*wC; qv[3] += tk*wD;
        }
      }
      float q[8];
      #pragma unroll
      for (int h = 0; h < 4; h++) { q[2*h] = qv[h][0]; q[2*h+1] = qv[h][1]; }
      float sq[8];
      #pragma unroll
      for (int o = 0; o < 8; o++) sq[o] = mij ? q[o] : 0.f;
      // sum tree via DPP + single DS shfl for the 16-offset
      #pragma unroll
      for (int o = 0; o < 8; o++) sq[o] += dppx<XOR1>(sq[o]);
      #pragma unroll
      for (int o = 0; o < 8; o++) sq[o] += dppx<XOR2>(sq[o]);
      #pragma unroll
      for (int o = 0; o < 8; o++) sq[o] += dppx<HMIR>(sq[o]);
      #pragma unroll
      for (int o = 0; o < 8; o++) sq[o] += dppx<MIR >(sq[o]);
      #pragma unroll
      for (int o = 0; o < 8; o++) sq[o] += __shfl_xor(sq[o], 16, 32);
      float qd[8];
      #pragma unroll
      for (int o = 0; o < 8; o++) qd[o] = __shfl(q[o], i, 32);
      float F[8];
      if (diag) {
        #pragma unroll
        for (int o = 0; o < 8; o++) F[o] = fmaxf(sq[o]*in_, 0.f);
      } else {
        float scl = mij ? 0.5f : 1.0f;
        #pragma unroll
        for (int o = 0; o < 8; o++)
          F[o] = fmaxf((q[o] + (mij ? qd[o] : 0.f))*scl, 0.f);
      }
      // max tree via DPP + single DS shfl (max is order-independent)
      #pragma unroll
      for (int o = 0; o < 8; o++) F[o] = fmaxf(F[o], dppx<XOR1>(F[o]));
      #pragma unroll
      for (int o = 0; o < 8; o++) F[o] = fmaxf(F[o], dppx<XOR2>(F[o]));
      #pragma unroll
      for (int o = 0; o < 8; o++) F[o] = fmaxf(F[o], dppx<HMIR>(F[o]));
      #pragma unroll
      for (int o = 0; o < 8; o++) F[o] = fmaxf(F[o], dppx<MIR >(F[o]));
      #pragma unroll
      for (int o = 0; o < 8; o++) F[o] = fmaxf(F[o], __shfl_xor(F[o], 16, 32));
      if (j == 0) {
        // write own pooled half straight to ws from P3 tail
        const int slw = (mybase + (t & 1))*SLOT;
        #pragma unroll
        for (int o = 0; o < 8; o++) {
          phbuf[i][myM*GO + o] = F[o];
          atomicExch(ws + slw + i*8 + o, F[o]);
        }
      }
    }
    __syncthreads();   // drains vmcnt in every wave -> pooled data globally visible

    // ---- exchange (double-buffered by t parity), overlapped with mlp1 h2-part ----
    const int sl  = (mybase + (t & 1))*SLOT;
    const int psl = (pbase  + (t & 1))*SLOT;
    if (tid == 0) atomicExch((unsigned*)(ws + sl + 256), (unsigned)(t + 1));
    asm volatile("" ::: "memory");
    // P4 phase A: mlp1 partial, k = 0..31 (h2 part only -> summation order identical in both blocks)
    const int p4 = grp32, u4 = lane;
    float m1lo = bm1l[u4], m1hi = bm1l[32 + u4];
    {
      #pragma unroll
      for (int c = 0; c < 8; c++) {
        float4 v = *(const float4*)&h2buf[p4][c*4];
        unsigned w0 = Wm1p[c*4+0][u4], w1 = Wm1p[c*4+1][u4];
        unsigned w2 = Wm1p[c*4+2][u4], w3 = Wm1p[c*4+3][u4];
        m1lo = fmaf(v.x, lo16(w0), m1lo); m1hi = fmaf(v.x, hi16(w0), m1hi);
        m1lo = fmaf(v.y, lo16(w1), m1lo); m1hi = fmaf(v.y, hi16(w1), m1hi);
        m1lo = fmaf(v.z, lo16(w2), m1lo); m1hi = fmaf(v.z, hi16(w2), m1hi);
        m1lo = fmaf(v.w, lo16(w3), m1lo); m1hi = fmaf(v.w, hi16(w3), m1hi);
      }
    }
    asm volatile("" ::: "memory");
    if (tid == 0) {
      while (atomicAdd((unsigned*)(ws + psl + 256), 0u) != (unsigned)(t + 1))
        __builtin_amdgcn_s_sleep(2);
    }
    __syncthreads();
    if (tid < 256) {
      int p = tid >> 3, o = tid & 7;
      phbuf[p][(1-myM)*8 + o] = atomicAdd(ws + psl + tid, 0.0f);
    }
    __syncthreads();

    // P4 phase B: k = 32..47 in ascending order (deterministic across both blocks), then mlp2
    {
      float4 f0 = *(const float4*)&phbuf[p4][0];
      float4 f1 = *(const float4*)&phbuf[p4][4];
      float4 f2 = *(const float4*)&phbuf[p4][8];
      float4 f3 = *(const float4*)&phbuf[p4][12];
      float pv[16] = {f0.x,f0.y,f0.z,f0.w, f1.x,f1.y,f1.z,f1.w,
                      f2.x,f2.y,f2.z,f2.w, f3.x,f3.y,f3.z,f3.w};
      #pragma unroll
      for (int k = 0; k < 16; k++) {
        unsigned v = Wm1p[32 + k][u4];
        m1lo = fmaf(pv[k], lo16(v), m1lo);
        m1hi = fmaf(pv[k], hi16(v), m1hi);
      }
      m1lo = fmaxf(m1lo, 0.f); m1hi = fmaxf(m1hi, 0.f);
      // mlp2 via wave-synchronous LDS stage (2 writes + 16 broadcast b128)
      float* mb = uni + 2048 + p4*64;   // overlays dead gate half of uni (a1 is dead after P3)
      mb[u4]      = m1lo;
      mb[32 + u4] = m1hi;
      float acc = bm2l[u4];
      #pragma unroll
      for (int k4 = 0; k4 < 8; k4++) {
        float4 lo4 = *(const float4*)(mb + k4*4);
        float4 hi4 = *(const float4*)(mb + 32 + k4*4);
        unsigned v0 = Wm2p[k4*4+0][u4], v1 = Wm2p[k4*4+1][u4];
        unsigned v2 = Wm2p[k4*4+2][u4], v3 = Wm2p[k4*4+3][u4];
        acc = fmaf(lo4.x, lo16(v0), acc); acc = fmaf(hi4.x, hi16(v0), acc);
        acc = fmaf(lo4.y, lo16(v1), acc); acc = fmaf(hi4.y, hi16(v1), acc);
        acc = fmaf(lo4.z, lo16(v2), acc); acc = fmaf(hi4.z, hi16(v2), acc);
        acc = fmaf(lo4.w, lo16(v3), acc); acc = fmaf(hi4.w, hi16(v3), acc);
      }
      hbuf[p4][u4] = fmaxf(acc, 0.f);
    }
    __syncthreads();
  }
}

// ==================== mono fallback: 128 blocks (R4 kernel, verified) ====================
__global__ __launch_bounds__(1024, 1) void decoder_kernel_mono(
    const float* __restrict__ last_pos, const float* __restrict__ last_pos_rel,
    const float* __restrict__ hh, const float* __restrict__ ch,
    const int*  __restrict__ eg,
    const float* __restrict__ W_se, const float* __restrict__ b_se,
    const float* __restrict__ Wih, const float* __restrict__ Whh,
    const float* __restrict__ bih, const float* __restrict__ bhh,
    const float* __restrict__ W_hp, const float* __restrict__ b_hp,
    const float* __restrict__ W_pse, const float* __restrict__ b_pse,
    const float* __restrict__ W1a, const float* __restrict__ W2a,
    const float* __restrict__ W1b, const float* __restrict__ W2b,
    const float* __restrict__ W_m1, const float* __restrict__ b_m1,
    const float* __restrict__ W_m2, const float* __restrict__ b_m2,
    float* __restrict__ out)
{
  const int tid   = threadIdx.x;
  const int scn   = blockIdx.x;
  const int lane  = tid & 31;
  const int grp32 = tid >> 5;

  __shared__ __align__(16) float uni[4864];
  __shared__ __align__(16) unsigned W1p[2][16][GH];
  __shared__ __align__(16) float W2l[2][GH][GO];
  __shared__ __align__(16) float Wp1[2][2][GH];
  __shared__ __align__(16) float c1l[2][GH];
  __shared__ __align__(16) float hbuf[NP][HD];
  __shared__ __align__(16) float h2buf[NP][36];
  __shared__ __align__(16) float GS[2][5][GH];
  __shared__ __align__(16) float phbuf[NP][16];
  __shared__ __align__(16) unsigned Wm1p[48][32];
  __shared__ __align__(16) unsigned Wm2p[32][32];
  __shared__ float lpbuf[NP][2], rpbuf[NP][2], Whp[HD][2];
  __shared__ float bm1l[MD], bm2l[HD], bhp2[2];
  __shared__ unsigned bm[2][NP];
  __shared__ float invn[2][NP];
  __shared__ int gl[NP];

  const int myrow = tid & 127;
  const int pq4   = tid >> 7;
  float wrow[HD];
  #pragma unroll
  for (int c = 0; c < HD/4; c++) {
    float4 w = *(const float4*)(Whh + myrow*HD + c*4);
    wrow[c*4+0]=w.x; wrow[c*4+1]=w.y; wrow[c*4+2]=w.z; wrow[c*4+3]=w.w;
  }
  float wf0 = 0.f, wf1 = 0.f, bfr = bih[myrow] + bhh[myrow];
  #pragma unroll
  for (int e = 0; e < ED; e++) {
    float wv = Wih[myrow*ED + e];
    wf0 = fmaf(W_se[e],    wv, wf0);
    wf1 = fmaf(W_se[ED+e], wv, wf1);
    bfr = fmaf(b_se[e],    wv, bfr);
  }
  float creg = ch[(scn*NP + grp32)*HD + lane];
  hbuf[grp32][lane] = hh[(scn*NP + grp32)*HD + lane];

  if (tid < NP) {
    int gi = eg[scn*NP + tid];
    gl[tid] = gi;
    unsigned sm = 0;
    for (int j = 0; j < NP; j++) {
      int gj = eg[scn*NP + j];
      bool sj = (j == tid) || (gi == gj && gi != 0);
      sm |= ((unsigned)sj) << j;
    }
    unsigned dm = (~sm) | (1u << tid);
    bm[0][tid] = sm; bm[1][tid] = dm;
    invn[0][tid] = 1.0f/(float)__popc(sm);
    invn[1][tid] = 1.0f/(float)__popc(dm);
  }
  if (tid < 64) {
    int p = tid >> 1, k = tid & 1;
    lpbuf[p][k] = last_pos[(scn*NP+p)*2+k];
    rpbuf[p][k] = last_pos_rel[(scn*NP+p)*2+k];
    Whp[p][k]   = W_hp[tid];
    bm1l[tid]   = b_m1[tid];
  }
  if (tid < 32) bm2l[tid] = b_m2[tid];
  if (tid < 2)  bhp2[tid] = b_hp[tid];
  if (tid < 2*GH) {
    int m = tid / GH, d = tid % GH;
    const float* W1 = m ? W1b : W1a;
    float s0 = 0.f, s1 = 0.f, sc1 = 0.f;
    for (int e = 0; e < ED; e++) {
      float w = W1[e*GH + d];
      s0 += W_pse[e]*w; s1 += W_pse[ED+e]*w; sc1 += b_pse[e]*w;
    }
    Wp1[m][0][d] = s0; Wp1[m][1][d] = s1; c1l[m][d] = sc1;
  }
  {
    int u = tid;
    if (u < 2*GH*GO) {
      int m = u/(GH*GO), rest = u%(GH*GO);
      W2l[m][rest/GO][rest%GO] = (m ? W2b : W2a)[rest];
    }
    if (tid < 128) {
      int u2 = tid + 1024;
      int m = u2/(GH*GO), rest = u2%(GH*GO);
      W2l[m][rest/GO][rest%GO] = (m ? W2b : W2a)[rest];
    }
  }
  #pragma unroll
  for (int r = 0; r < 3; r++) {
    int u = tid + 1024*r;
    if (u < 2304) {
      int m = u/1152, rest = u%1152, k2 = rest/GH, d = rest%GH;
      const float* W1 = m ? W1b : W1a;
      W1p[m][k2][d] = rne16(W1[(ED+2*k2)*GH + d]) | (rne16(W1[(ED+2*k2+1)*GH + d]) << 16);
    }
  }
  #pragma unroll
  for (int r = 0; r < 2; r++) {
    int u = tid + 1024*r;
    if (u < 1536) {
      int k = u >> 5, uu = u & 31;
      Wm1p[k][uu] = rne16(W_m1[k*MD + uu]) | (rne16(W_m1[k*MD + 32 + uu]) << 16);
    }
  }
  {
    int k = tid >> 5, uu = tid & 31;
    Wm2p[k][uu] = rne16(W_m2[k*HD + uu]) | (rne16(W_m2[(k+32)*HD + uu]) << 16);
  }
  __syncthreads();

  for (int t = 0; t < TT; t++) {
    {
      float rG[4];
      #pragma unroll
      for (int pp2 = 0; pp2 < 4; pp2++) {
        int p = pq4*4 + pp2;
        float acc = fmaf(rpbuf[p][0], wf0, fmaf(rpbuf[p][1], wf1, bfr));
        #pragma unroll
        for (int c = 0; c < 8; c++) {
          float4 h4 = *(const float4*)&hbuf[p][c*4];
          acc = fmaf(h4.x, wrow[c*4+0], acc);
          acc = fmaf(h4.y, wrow[c*4+1], acc);
          acc = fmaf(h4.z, wrow[c*4+2], acc);
          acc = fmaf(h4.w, wrow[c*4+3], acc);
        }
        rG[pp2] = acc;
      }
      #pragma unroll
      for (int pp2 = 0; pp2 < 4; pp2++) uni[(pq4*4+pp2)*128 + myrow] = rG[pp2];
    }
    __syncthreads();
    {
      int p = grp32, n = lane;
      float gi_ = uni[p*128 + n];
      float gf_ = uni[p*128 + 32 + n];
      float gg_ = uni[p*128 + 64 + n];
      float go_ = uni[p*128 + 96 + n];
      float c2 = sigm(gf_)*creg + sigm(gi_)*tanhfast(gg_);
      creg = c2;
      float h2 = sigm(go_)*tanhfast(c2);
      h2buf[p][n] = h2;
      float r0 = h2 * Whp[n][0];
      float r1 = h2 * Whp[n][1];
      #pragma unroll
      for (int off = 1; off < 32; off <<= 1) {
        r0 += __shfl_xor(r0, off, 32);
        r1 += __shfl_xor(r1, off, 32);
      }
      r0 += bhp2[0]; r1 += bhp2[1];
      if (n == 0) {
        out[t*NB*2 + (scn*NP+p)*2 + 0] = r0;
        out[t*NB*2 + (scn*NP+p)*2 + 1] = r1;
        rpbuf[p][0] = r0;  rpbuf[p][1] = r1;
        lpbuf[p][0] += r0; lpbuf[p][1] += r1;
      }
    }
    __syncthreads();
    {
      const int j = lane;
      float lpj0 = lpbuf[j][0], lpj1 = lpbuf[j][1];
      float h2row[HD];
      #pragma unroll
      for (int c = 0; c < 8; c++) {
        float4 v = *(const float4*)&h2buf[j][c*4];
        h2row[c*4+0]=v.x; h2row[c*4+1]=v.y; h2row[c*4+2]=v.z; h2row[c*4+3]=v.w;
      }
      #pragma unroll
      for (int r = 0; r < 5; r++) {
        int rest = grp32 + 32*r;
        if (rest < 144) {
          int m = rest >= 72 ? 1 : 0;
          int d = rest - 72*m;
          float pp_ = fmaf(lpj0, Wp1[m][0][d], lpj1*Wp1[m][1][d]);
          float av = pp_;
          #pragma unroll
          for (int k2 = 0; k2 < 16; k2++) {
            unsigned v = W1p[m][k2][d];
            av = fmaf(h2row[2*k2], lo16(v), av);
            av = fmaf(h2row[2*k2+1], hi16(v), av);
          }
          uni[m*2432 + j*76 + d] = av;
          int gj = gl[j];
          float tot = av;
          float s1 = (gj==1)?av:0.f, s2=(gj==2)?av:0.f, s3=(gj==3)?av:0.f, s4=(gj==4)?av:0.f;
          #pragma unroll
          for (int off = 1; off < 32; off <<= 1) {
            tot += __shfl_xor(tot, off, 32);
            s1 += __shfl_xor(s1, off, 32);
            s2 += __shfl_xor(s2, off, 32);
            s3 += __shfl_xor(s3, off, 32);
            s4 += __shfl_xor(s4, off, 32);
          }
          if (j < 5) {
            float v2;
            if (m == 0) v2 = (j==0)?tot:((j==1)?s1:((j==2)?s2:((j==3)?s3:s4)));
            else        v2 = (j==0)?tot:((j==1)?tot-s1:((j==2)?tot-s2:((j==3)?tot-s3:tot-s4)));
            GS[m][j][d] = v2;
          }
        }
      }
    }
    __syncthreads();
    {
      const int j   = lane;
      const int m   = tid >> 9;
      const int sub = (tid >> 5) & 15;
      const float* am = uni + m*2432;
      int   I2[2] = {sub, sub + 16};
      const float *P0[2], *P1[2];
      float C0[2], C1[2], NL0[2], NL1[2];
      bool  MIJ[2], DIAG[2];
      v2f qv[2][4];
      #pragma unroll
      for (int r = 0; r < 2; r++) {
        int i = I2[r];
        unsigned bmv = bm[m][i];
        bool mij = (bmv >> j) & 1u;
        bool diag = (j == i);
        int gi = gl[i];
        float in_ = invn[m][i];
        const float *p0, *p1; float c0, c1c;
        if (diag) {
          if (m == 0) { p0 = gi ? &GS[0][gi][0] : (am + i*76); c0 = in_; p1 = am + i*76; c1c = 0.f; }
          else        { p0 = &GS[1][gi][0];                    c0 = in_; p1 = am + i*76; c1c = gi ? in_ : 0.f; }
        } else if (mij) { p0 = am + j*76; c0 = 0.5f; p1 = am + i*76; c1c = 0.5f; }
        else            { p0 = am + j*76; c0 = 1.0f; p1 = am + j*76; c1c = 0.f; }
        P0[r]=p0; P1[r]=p1; C0[r]=c0; C1[r]=c1c; MIJ[r]=mij; DIAG[r]=diag;
        NL0[r] = -lpbuf[i][0]; NL1[r] = -lpbuf[i][1];
        #pragma unroll
        for (int h = 0; h < 4; h++) qv[r][h] = (v2f){0.f, 0.f};
      }
      for (int d4 = 0; d4 < GH/4; d4++) {
        float4 c14 = *(const float4*)&c1l[m][d4*4];
        float4 w04 = *(const float4*)&Wp1[m][0][d4*4];
        float4 w14 = *(const float4*)&Wp1[m][1][d4*4];
        float4 vaS = *(const float4*)(am + j*76 + d4*4);
        float4 va0 = vaS, va1 = vaS;
        if (DIAG[0]) va0 = *(const float4*)(P0[0] + d4*4);
        if (DIAG[1]) va1 = *(const float4*)(P0[1] + d4*4);
        float4 vb0 = *(const float4*)(P1[0] + d4*4);
        float4 vb1 = *(const float4*)(P1[1] + d4*4);
        float e0x = fmaf(NL1[0], w14.x, fmaf(NL0[0], w04.x, c14.x));
        float e0y = fmaf(NL1[0], w14.y, fmaf(NL0[0], w04.y, c14.y));
        float e0z = fmaf(NL1[0], w14.z, fmaf(NL0[0], w04.z, c14.z));
        float e0w = fmaf(NL1[0], w14.w, fmaf(NL0[0], w04.w, c14.w));
        float e1x = fmaf(NL1[1], w14.x, fmaf(NL0[1], w04.x, c14.x));
        float e1y = fmaf(NL1[1], w14.y, fmaf(NL0[1], w04.y, c14.y));
        float e1z = fmaf(NL1[1], w14.z, fmaf(NL0[1], w04.z, c14.z));
        float e1w = fmaf(NL1[1], w14.w, fmaf(NL0[1], w04.w, c14.w));
        float tv0[4], tv1[4];
        tv0[0] = fmaxf(fmaf(C0[0], va0.x, fmaf(C1[0], vb0.x, e0x)), 0.f);
        tv0[1] = fmaxf(fmaf(C0[0], va0.y, fmaf(C1[0], vb0.y, e0y)), 0.f);
        tv0[2] = fmaxf(fmaf(C0[0], va0.z, fmaf(C1[0], vb0.z, e0z)), 0.f);
        tv0[3] = fmaxf(fmaf(C0[0], va0.w, fmaf(C1[0], vb0.w, e0w)), 0.f);
        tv1[0] = fmaxf(fmaf(C0[1], va1.x, fmaf(C1[1], vb1.x, e1x)), 0.f);
        tv1[1] = fmaxf(fmaf(C0[1], va1.y, fmaf(C1[1], vb1.y, e1y)), 0.f);
        tv1[2] = fmaxf(fmaf(C0[1], va1.z, fmaf(C1[1], vb1.z, e1z)), 0.f);
        tv1[3] = fmaxf(fmaf(C0[1], va1.w, fmaf(C1[1], vb1.w, e1w)), 0.f);
        #pragma unroll
        for (int k = 0; k < 4; k++) {
          const v2f* w2p = (const v2f*)&W2l[m][d4*4+k][0];
          v2f wA = w2p[0], wB = w2p[1], wC = w2p[2], wD = w2p[3];
          v2f t0 = {tv0[k], tv0[k]};
          qv[0][0] += t0*wA; qv[0][1] += t0*wB; qv[0][2] += t0*wC; qv[0][3] += t0*wD;
          v2f t1 = {tv1[k], tv1[k]};
          qv[1][0] += t1*wA; qv[1][1] += t1*wB; qv[1][2] += t1*wC; qv[1][3] += t1*wD;
        }
      }
      #pragma unroll
      for (int r = 0; r < 2; r++) {
        float q[8];
        #pragma unroll
        for (int h = 0; h < 4; h++) { q[2*h] = qv[r][h][0]; q[2*h+1] = qv[r][h][1]; }
        float sq[8];
        #pragma unroll
        for (int o = 0; o < 8; o++) sq[o] = MIJ[r] ? q[o] : 0.f;
        #pragma unroll
        for (int off = 1; off < 32; off <<= 1) {
          #pragma unroll
          for (int o = 0; o < 8; o++) sq[o] += __shfl_xor(sq[o], off, 32);
        }
        float qd[8];
        #pragma unroll
        for (int o = 0; o < 8; o++) qd[o] = __shfl(q[o], I2[r], 32);
        float in_ = invn[m][I2[r]];
        float F[8];
        if (DIAG[r]) {
          #pragma unroll
          for (int o = 0; o < 8; o++) F[o] = fmaxf(sq[o]*in_, 0.f);
        } else {
          float scl = MIJ[r] ? 0.5f : 1.0f;
          #pragma unroll
          for (int o = 0; o < 8; o++)
            F[o] = fmaxf((q[o] + (MIJ[r] ? qd[o] : 0.f))*scl, 0.f);
        }
        #pragma unroll
        for (int off = 1; off < 32; off <<= 1) {
          #pragma unroll
          for (int o = 0; o < 8; o++) F[o] = fmaxf(F[o], __shfl_xor(F[o], off, 32));
        }
        if (j == 0) {
          #pragma unroll
          for (int o = 0; o < 8; o++) phbuf[I2[r]][m*GO + o] = F[o];
        }
      }
    }
    __syncthreads();
    {
      int p = grp32, u = lane;
      float in48[48];
      #pragma unroll
      for (int c = 0; c < 8; c++) {
        float4 v = *(const float4*)&h2buf[p][c*4];
        in48[c*4+0]=v.x; in48[c*4+1]=v.y; in48[c*4+2]=v.z; in48[c*4+3]=v.w;
      }
      #pragma unroll
      for (int c = 0; c < 4; c++) {
        float4 v = *(const float4*)&phbuf[p][c*4];
        in48[32+c*4+0]=v.x; in48[32+c*4+1]=v.y; in48[32+c*4+2]=v.z; in48[32+c*4+3]=v.w;
      }
      float m1lo = bm1l[u], m1hi = bm1l[32 + u];
      #pragma unroll
      for (int k = 0; k < 48; k++) {
        unsigned v = Wm1p[k][u];
        m1lo = fmaf(in48[k], lo16(v), m1lo);
        m1hi = fmaf(in48[k], hi16(v), m1hi);
      }
      m1lo = fmaxf(m1lo, 0.f); m1hi = fmaxf(m1hi, 0.f);
      float acc = bm2l[u];
      #pragma unroll
      for (int k = 0; k < 32; k++) {
        unsigned v = Wm2p[k][u];
        acc = fmaf(__shfl(m1lo, k, 32), lo16(v), acc);
        acc = fmaf(__shfl(m1hi, k, 32), hi16(v), acc);
      }
      hbuf[p][u] = fmaxf(acc, 0.f);
    }
    __syncthreads();
  }
}

extern "C" void kernel_launch(void* const* d_in, const int* in_sizes, int n_in,
                              void* d_out, int out_size, void* d_ws, size_t ws_size,
                              hipStream_t stream) {
  (void)in_sizes; (void)n_in; (void)out_size;
  const float* last_pos     = (const float*)d_in[0];
  const float* last_pos_rel = (const float*)d_in[1];
  const float* hh           = (const float*)d_in[2];
  const float* ch           = (const float*)d_in[3];
  const int*  eg            = (const int*) d_in[5];
  const float* W_se  = (const float*)d_in[6];
  const float* b_se  = (const float*)d_in[7];
  const float* Wih   = (const float*)d_in[8];
  const float* Whh   = (const float*)d_in[9];
  const float* bih   = (const float*)d_in[10];
  const float* bhh   = (const float*)d_in[11];
  const float* W_hp  = (const float*)d_in[12];
  const float* b_hp  = (const float*)d_in[13];
  const float* W_pse = (const float*)d_in[14];
  const float* b_pse = (const float*)d_in[15];
  const float* W1a   = (const float*)d_in[16];
  const float* W2a   = (const float*)d_in[17];
  const float* W1b   = (const float*)d_in[18];
  const float* W2b   = (const float*)d_in[19];
  const float* W_m1  = (const float*)d_in[20];
  const float* b_m1  = (const float*)d_in[21];
  const float* W_m2  = (const float*)d_in[22];
  const float* b_m2  = (const float*)d_in[23];
  float* out = (float*)d_out;

  if (ws_size >= (size_t)WS_NEED) {
    decoder_kernel_split<<<2*NS, 1024, 0, stream>>>(
        last_pos, last_pos_rel, hh, ch, eg,
        W_se, b_se, Wih, Whh, bih, bhh, W_hp, b_hp, W_pse, b_pse,
        W1a, W2a, W1b, W2b, W_m1, b_m1, W_m2, b_m2, out, (float*)d_ws);
  } else {
    decoder_kernel_mono<<<NS, 1024, 0, stream>>>(
        last_pos, last_pos_rel, hh, ch, eg,
        W_se, b_se, Wih, Whh, bih, bhh, W_hp, b_hp, W_pse, b_pse,
        W1a, W2a, W1b, W2b, W_m1, b_m1, W_m2, b_m2, out);
  }
}

// Round 11
// 235.105 us; speedup vs baseline: 1.0291x; 1.0291x over previous
//
#include <hip/hip_runtime.h>

#define NS 128
#define NP 32
#define HD 32
#define ED 16
#define GH 72
#define GO 8
#define MD 64
#define TT 8
#define NB (NS*NP)
#define EW 76

#define SLOT 272   // floats per slot: 256 data + flag + pad
// 256 blocks x 2 parity slots
#define WS_NEED (256*2*SLOT*4)

typedef float v2f __attribute__((ext_vector_type(2)));

__device__ __forceinline__ float sigm(float x){ return 1.0f/(1.0f+__expf(-x)); }
__device__ __forceinline__ float tanhfast(float x){ return 1.0f - 2.0f/(__expf(2.0f*x)+1.0f); }
__device__ __forceinline__ unsigned rne16(float f){
  unsigned u = __float_as_uint(f);
  u += 0x7fffu + ((u>>16)&1u);
  return u>>16;
}
__device__ __forceinline__ float lo16(unsigned v){ return __uint_as_float(v<<16); }
__device__ __forceinline__ float hi16(unsigned v){ return __uint_as_float(v & 0xffff0000u); }
// DPP cross-lane move (VALU pipe).
// 0xB1 = quad_perm xor1, 0x4E = quad_perm xor2,
// 0x141 = row_half_mirror (8-sum after xor1/xor2), 0x140 = row_mirror (16-sum).
template<int C>
__device__ __forceinline__ float dppx(float x){
  return __int_as_float(__builtin_amdgcn_update_dpp(0, __float_as_int(x), C, 0xF, 0xF, true));
}
#define XOR1 0xB1
#define XOR2 0x4E
#define HMIR 0x141
#define MIR  0x140
// full 32-lane sum: 4 DPP levels + one DS shfl for the 16-offset
__device__ __forceinline__ float wsum32(float v){
  v += dppx<XOR1>(v);
  v += dppx<XOR2>(v);
  v += dppx<HMIR>(v);
  v += dppx<MIR >(v);
  v += __shfl_xor(v, 16, 32);
  return v;
}

// ==================== split kernel: 256 blocks, (scene, m) per block ====================
__global__ __launch_bounds__(1024, 1) void decoder_kernel_split(
    const float* __restrict__ last_pos, const float* __restrict__ last_pos_rel,
    const float* __restrict__ hh, const float* __restrict__ ch,
    const int*  __restrict__ eg,
    const float* __restrict__ W_se, const float* __restrict__ b_se,
    const float* __restrict__ Wih, const float* __restrict__ Whh,
    const float* __restrict__ bih, const float* __restrict__ bhh,
    const float* __restrict__ W_hp, const float* __restrict__ b_hp,
    const float* __restrict__ W_pse, const float* __restrict__ b_pse,
    const float* __restrict__ W1a, const float* __restrict__ W2a,
    const float* __restrict__ W1b, const float* __restrict__ W2b,
    const float* __restrict__ W_m1, const float* __restrict__ b_m1,
    const float* __restrict__ W_m2, const float* __restrict__ b_m2,
    float* __restrict__ out, float* __restrict__ ws)
{
  const int tid   = threadIdx.x;
  const int scn   = blockIdx.x >> 1;
  const int myM   = blockIdx.x & 1;
  const int lane  = tid & 31;
  const int grp32 = tid >> 5;      // 0..31

  // uni overlays: G[32][128] gate staging (16 KB) <-> a1[32][76] (9.7 KB) <-> m1-stage (P4, uni+2048)
  __shared__ __align__(16) float uni[4096];
  __shared__ __align__(16) unsigned W1pT[GH][16];  // own m, bf16 pairs, TRANSPOSED (row d = 16 dwords)
  __shared__ __align__(16) float Wp1[2][GH];       // own m
  __shared__ __align__(16) float c1l[GH];          // own m
  __shared__ __align__(16) float ebuf[NP*EW];      // e[i][d] = c1 - lp[i].Wp1  (P3 coef precompute)
  __shared__ __align__(16) float hbuf[NP][HD];
  __shared__ __align__(16) float h2buf[NP][36];
  __shared__ __align__(16) float GS[5][GH];        // own m
  __shared__ __align__(16) float phbuf[NP][16];
  __shared__ __align__(16) unsigned Wm1p[48][32];
  __shared__ __align__(16) unsigned Wm2p[32][32];
  __shared__ float lpbuf[NP][2], rpbuf[NP][2], Whp[HD][2];
  __shared__ float bm1l[MD], bm2l[HD], bhp2[2];
  __shared__ unsigned bm[NP];
  __shared__ unsigned gmsk[5];                     // group membership masks (g=0 -> all)
  __shared__ float invn[NP];
  __shared__ int gl[NP];

  float* const a1 = uni;   // [32][76]

  const int mybase = (scn*2 + myM)*2;       // slot-pair index (x SLOT)
  const int pbase  = (scn*2 + 1 - myM)*2;

  // ---------- persistent per-thread LSTM row weights (global read ONCE) ----------
  const int myrow = tid & 127;
  const int pq4   = tid >> 7;
  float wrow[HD];
  #pragma unroll
  for (int c = 0; c < HD/4; c++) {
    float4 w = *(const float4*)(Whh + myrow*HD + c*4);
    wrow[c*4+0]=w.x; wrow[c*4+1]=w.y; wrow[c*4+2]=w.z; wrow[c*4+3]=w.w;
  }
  float wf0 = 0.f, wf1 = 0.f, bfr = bih[myrow] + bhh[myrow];
  #pragma unroll
  for (int e = 0; e < ED; e++) {
    float wv = Wih[myrow*ED + e];
    wf0 = fmaf(W_se[e],    wv, wf0);
    wf1 = fmaf(W_se[ED+e], wv, wf1);
    bfr = fmaf(b_se[e],    wv, bfr);
  }

  float creg = ch[(scn*NP + grp32)*HD + lane];
  hbuf[grp32][lane] = hh[(scn*NP + grp32)*HD + lane];

  // ---------- setup ----------
  if (tid < NP) {
    int gi = eg[scn*NP + tid];
    gl[tid] = gi;
    unsigned sm = 0;
    for (int j = 0; j < NP; j++) {
      int gj = eg[scn*NP + j];
      bool sj = (j == tid) || (gi == gj && gi != 0);
      sm |= ((unsigned)sj) << j;
    }
    unsigned mk = myM ? ((~sm) | (1u << tid)) : sm;
    bm[tid] = mk;
    invn[tid] = 1.0f/(float)__popc(mk);
  }
  if (tid < 5) {       // membership mask per group id
    unsigned mv = 0;
    for (int j = 0; j < NP; j++) if (eg[scn*NP + j] == tid) mv |= (1u << j);
    gmsk[tid] = (tid == 0) ? 0xFFFFFFFFu : mv;
  }
  if (tid < 64) {
    int p = tid >> 1, k = tid & 1;
    lpbuf[p][k] = last_pos[(scn*NP+p)*2+k];
    rpbuf[p][k] = last_pos_rel[(scn*NP+p)*2+k];
    Whp[p][k]   = W_hp[tid];
    bm1l[tid]   = b_m1[tid];
  }
  if (tid < 32) bm2l[tid] = b_m2[tid];
  if (tid < 2)  bhp2[tid] = b_hp[tid];
  const float* W1my = myM ? W1b : W1a;
  const float* W2g  = myM ? W2b : W2a;    // W2 read from GLOBAL with uniform index -> s_load, off the DS pipe
  if (tid < GH) {   // folded Wp1 = W_pse@W1[:16], c1 = b_pse@W1[:16] (own m)
    int d = tid;
    float s0 = 0.f, s1 = 0.f, sc1 = 0.f;
    for (int e = 0; e < ED; e++) {
      float w = W1my[e*GH + d];
      s0  += W_pse[e]    * w;
      s1  += W_pse[ED+e] * w;
      sc1 += b_pse[e]    * w;
    }
    Wp1[0][d] = s0; Wp1[1][d] = s1; c1l[d] = sc1;
  }
  #pragma unroll
  for (int r = 0; r < 2; r++) {  // W1pT own m, packed bf16, transposed (1152 > 1024: TWO passes)
    int u = tid + 1024*r;
    if (u < 16*GH) {
      int k2 = u/GH, d = u%GH;
      unsigned lo = rne16(W1my[(ED+2*k2  )*GH + d]);
      unsigned hi = rne16(W1my[(ED+2*k2+1)*GH + d]);
      W1pT[d][k2] = lo | (hi << 16);
    }
  }
  #pragma unroll
  for (int r = 0; r < 2; r++) {   // Wm1p packed bf16 (1536)
    int u = tid + 1024*r;
    if (u < 1536) {
      int k = u >> 5, uu = u & 31;
      Wm1p[k][uu] = rne16(W_m1[k*MD + uu]) | (rne16(W_m1[k*MD + 32 + uu]) << 16);
    }
  }
  {  // Wm2p packed bf16 (1024)
    int k = tid >> 5, uu = tid & 31;
    Wm2p[k][uu] = rne16(W_m2[k*HD + uu]) | (rne16(W_m2[(k+32)*HD + uu]) << 16);
  }
  __syncthreads();

  // ---------------- time steps ----------------
  for (int t = 0; t < TT; t++) {
    // P1a: gates[p][myrow] for 4 peds (redundant in both blocks; deterministic)
    // R15: b128-broadcast hbuf reads (wave-uniform addr -> conflict-free) instead of 128 readlanes;
    // halves P1a VALU ops, moves the traffic to the now-slack DS pipe. (Isolated test; rode in toxic R8 bundle before.)
    {
      float rG[4];
      #pragma unroll
      for (int pp2 = 0; pp2 < 4; pp2++) {
        int p = pq4*4 + pp2;
        float acc = fmaf(rpbuf[p][0], wf0, fmaf(rpbuf[p][1], wf1, bfr));
        #pragma unroll
        for (int c = 0; c < 8; c++) {
          float4 h4 = *(const float4*)&hbuf[p][c*4];
          acc = fmaf(h4.x, wrow[c*4+0], acc);
          acc = fmaf(h4.y, wrow[c*4+1], acc);
          acc = fmaf(h4.z, wrow[c*4+2], acc);
          acc = fmaf(h4.w, wrow[c*4+3], acc);
        }
        rG[pp2] = acc;
      }
      #pragma unroll
      for (int pp2 = 0; pp2 < 4; pp2++) uni[(pq4*4+pp2)*128 + myrow] = rG[pp2];
    }
    __syncthreads();

    // P1b: activations, c/h2 update; rel_pos reduction; out store (m=0 block only)
    {
      int p = grp32, n = lane;
      float gi_ = uni[p*128 +       n];
      float gf_ = uni[p*128 +  32 + n];
      float gg_ = uni[p*128 +  64 + n];
      float go_ = uni[p*128 +  96 + n];
      float c2 = sigm(gf_)*creg + sigm(gi_)*tanhfast(gg_);
      creg = c2;
      float h2 = sigm(go_)*tanhfast(c2);
      h2buf[p][n] = h2;
      float r0 = h2 * Whp[n][0];
      float r1 = h2 * Whp[n][1];
      // full reduction tree on VALU via DPP, one DS shfl for the 16-offset
      r0 += dppx<XOR1>(r0); r1 += dppx<XOR1>(r1);
      r0 += dppx<XOR2>(r0); r1 += dppx<XOR2>(r1);
      r0 += dppx<HMIR>(r0); r1 += dppx<HMIR>(r1);
      r0 += dppx<MIR >(r0); r1 += dppx<MIR >(r1);
      r0 += __shfl_xor(r0, 16, 32);
      r1 += __shfl_xor(r1, 16, 32);
      r0 += bhp2[0]; r1 += bhp2[1];
      if (n == 0) {
        if (myM == 0) {
          out[t*NB*2 + (scn*NP+p)*2 + 0] = r0;
          out[t*NB*2 + (scn*NP+p)*2 + 1] = r1;
        }
        rpbuf[p][0] = r0;  rpbuf[p][1] = r1;
        lpbuf[p][0] += r0; lpbuf[p][1] += r1;
      }
    }
    __syncthreads();

    // P2: a1[j][d] + GS group sums via DPP trees + ebuf precompute
    {
      const int j = lane;
      float lpj0 = lpbuf[j][0], lpj1 = lpbuf[j][1];
      const int gj = gl[j];
      float h2row[HD];
      #pragma unroll
      for (int c = 0; c < 8; c++) {
        float4 v = *(const float4*)&h2buf[j][c*4];
        h2row[c*4+0]=v.x; h2row[c*4+1]=v.y; h2row[c*4+2]=v.z; h2row[c*4+3]=v.w;
      }
      #pragma unroll
      for (int r = 0; r < 3; r++) {
        int d = grp32 + 32*r;
        if (d < GH) {
          float av = fmaf(lpj0, Wp1[0][d], lpj1*Wp1[1][d]);
          #pragma unroll
          for (int k8 = 0; k8 < 4; k8++) {   // 4 half-wave-uniform b128
            uint4 w4 = *(const uint4*)&W1pT[d][k8*4];
            av = fmaf(h2row[k8*8+0], lo16(w4.x), av);
            av = fmaf(h2row[k8*8+1], hi16(w4.x), av);
            av = fmaf(h2row[k8*8+2], lo16(w4.y), av);
            av = fmaf(h2row[k8*8+3], hi16(w4.y), av);
            av = fmaf(h2row[k8*8+4], lo16(w4.z), av);
            av = fmaf(h2row[k8*8+5], hi16(w4.z), av);
            av = fmaf(h2row[k8*8+6], lo16(w4.w), av);
            av = fmaf(h2row[k8*8+7], hi16(w4.w), av);
          }
          a1[j*EW + d] = av;
          // GS via DPP trees (VALU), inline (P2b phase deleted)
          float tot = wsum32(av);
          float s1 = wsum32((gj==1) ? av : 0.f);
          float s2 = wsum32((gj==2) ? av : 0.f);
          float s3 = wsum32((gj==3) ? av : 0.f);
          float s4 = wsum32((gj==4) ? av : 0.f);
          if (j < 5) {
            float v2;
            if (myM == 0) v2 = (j==0)?tot:((j==1)?s1:((j==2)?s2:((j==3)?s3:s4)));
            else          v2 = (j==0)?tot:((j==1)?tot-s1:((j==2)?tot-s2:((j==3)?tot-s3:tot-s4)));
            GS[j][d] = v2;
          }
        }
      }
      // e[i][d] precompute
      #pragma unroll
      for (int ii = 0; ii < 3; ii++) {
        int idx = tid + 1024*ii;
        if (idx < NP*GH) {
          int d = idx >> 5, i2 = idx & 31;
          ebuf[i2*EW + d] = fmaf(-lpbuf[i2][1], Wp1[1][d],
                            fmaf(-lpbuf[i2][0], Wp1[0][d], c1l[d]));
        }
      }
    }
    __syncthreads();

    // P3: pool (own m). One task per thread: i = grp32, j = lane.
    // Unroll-by-2 for ILP + packed-fp32 tv.
    {
      const int j = lane, i = grp32;
      unsigned bmv = bm[i];
      bool mij = (bmv >> j) & 1u;
      bool diag = (j == i);
      int gi = gl[i];
      float in_ = invn[i];
      const float *p0, *p1; float c0, c1c;
      if (diag) {
        if (myM == 0) { p0 = gi ? &GS[gi][0] : (a1 + i*EW); c0 = in_; p1 = a1 + i*EW; c1c = 0.f; }
        else          { p0 = &GS[gi][0];                    c0 = in_; p1 = a1 + i*EW; c1c = gi ? in_ : 0.f; }
      } else if (mij) { p0 = a1 + j*EW; c0 = 0.5f; p1 = a1 + i*EW; c1c = 0.5f; }
      else            { p0 = a1 + j*EW; c0 = 1.0f; p1 = a1 + j*EW; c1c = 0.f; }
      const float* erow = ebuf + i*EW;
      const v2f c0v = (v2f){c0, c0};
      const v2f c1v = (v2f){c1c, c1c};
      v2f qv[4];
      #pragma unroll
      for (int h = 0; h < 4; h++) qv[h] = (v2f){0.f, 0.f};
      #pragma unroll 2
      for (int d4 = 0; d4 < GH/4; d4++) {
        float4 e4 = *(const float4*)(erow + d4*4);
        float4 va = diag ? *(const float4*)(p0 + d4*4)
                         : *(const float4*)(a1 + j*EW + d4*4);
        float4 vb = *(const float4*)(p1 + d4*4);
        // packed tv: t = relu(c0*va + (c1c*vb + e)) on v_pk_fma_f32/v_pk_max_f32
        v2f e01 = (v2f){e4.x, e4.y}, e23 = (v2f){e4.z, e4.w};
        v2f va01 = (v2f){va.x, va.y}, va23 = (v2f){va.z, va.w};
        v2f vb01 = (v2f){vb.x, vb.y}, vb23 = (v2f){vb.z, vb.w};
        v2f u01 = c1v*vb01 + e01;
        v2f u23 = c1v*vb23 + e23;
        v2f t01 = c0v*va01 + u01;
        v2f t23 = c0v*va23 + u23;
        t01 = (v2f){fmaxf(t01[0], 0.f), fmaxf(t01[1], 0.f)};
        t23 = (v2f){fmaxf(t23[0], 0.f), fmaxf(t23[1], 0.f)};
        float tv[4] = {t01[0], t01[1], t23[0], t23[1]};
        #pragma unroll
        for (int k = 0; k < 4; k++) {
          // uniform global reads -> s_load into SGPRs, zero DS traffic
          const float* wr = W2g + (d4*4+k)*GO;
          v2f wA = {wr[0], wr[1]}, wB = {wr[2], wr[3]};
          v2f wC = {wr[4], wr[5]}, wD = {wr[6], wr[7]};
          v2f tk = {tv[k], tv[k]};
          qv[0] += tk*wA; qv[1] += tk*wB; qv[2] += tk*wC; qv[3] += tk*wD;
        }
      }
      float q[8];
      #pragma unroll
      for (int h = 0; h < 4; h++) { q[2*h] = qv[h][0]; q[2*h+1] = qv[h][1]; }
      float sq[8];
      #pragma unroll
      for (int o = 0; o < 8; o++) sq[o] = mij ? q[o] : 0.f;
      // sum tree via DPP + single DS shfl for the 16-offset
      #pragma unroll
      for (int o = 0; o < 8; o++) sq[o] += dppx<XOR1>(sq[o]);
      #pragma unroll
      for (int o = 0; o < 8; o++) sq[o] += dppx<XOR2>(sq[o]);
      #pragma unroll
      for (int o = 0; o < 8; o++) sq[o] += dppx<HMIR>(sq[o]);
      #pragma unroll
      for (int o = 0; o < 8; o++) sq[o] += dppx<MIR >(sq[o]);
      #pragma unroll
      for (int o = 0; o < 8; o++) sq[o] += __shfl_xor(sq[o], 16, 32);
      float qd[8];
      #pragma unroll
      for (int o = 0; o < 8; o++) qd[o] = __shfl(q[o], i, 32);
      float F[8];
      if (diag) {
        #pragma unroll
        for (int o = 0; o < 8; o++) F[o] = fmaxf(sq[o]*in_, 0.f);
      } else {
        float scl = mij ? 0.5f : 1.0f;
        #pragma unroll
        for (int o = 0; o < 8; o++)
          F[o] = fmaxf((q[o] + (mij ? qd[o] : 0.f))*scl, 0.f);
      }
      // max tree via DPP + single DS shfl (max is order-independent)
      #pragma unroll
      for (int o = 0; o < 8; o++) F[o] = fmaxf(F[o], dppx<XOR1>(F[o]));
      #pragma unroll
      for (int o = 0; o < 8; o++) F[o] = fmaxf(F[o], dppx<XOR2>(F[o]));
      #pragma unroll
      for (int o = 0; o < 8; o++) F[o] = fmaxf(F[o], dppx<HMIR>(F[o]));
      #pragma unroll
      for (int o = 0; o < 8; o++) F[o] = fmaxf(F[o], dppx<MIR >(F[o]));
      #pragma unroll
      for (int o = 0; o < 8; o++) F[o] = fmaxf(F[o], __shfl_xor(F[o], 16, 32));
      if (j == 0) {
        // write own pooled half straight to ws from P3 tail
        const int slw = (mybase + (t & 1))*SLOT;
        #pragma unroll
        for (int o = 0; o < 8; o++) {
          phbuf[i][myM*GO + o] = F[o];
          atomicExch(ws + slw + i*8 + o, F[o]);
        }
      }
    }
    __syncthreads();   // drains vmcnt in every wave -> pooled data globally visible

    // ---- exchange (double-buffered by t parity), overlapped with mlp1 h2-part ----
    const int sl  = (mybase + (t & 1))*SLOT;
    const int psl = (pbase  + (t & 1))*SLOT;
    if (tid == 0) atomicExch((unsigned*)(ws + sl + 256), (unsigned)(t + 1));
    asm volatile("" ::: "memory");
    // P4 phase A: mlp1 partial, k = 0..31 (h2 part only -> summation order identical in both blocks)
    const int p4 = grp32, u4 = lane;
    float m1lo = bm1l[u4], m1hi = bm1l[32 + u4];
    {
      #pragma unroll
      for (int c = 0; c < 8; c++) {
        float4 v = *(const float4*)&h2buf[p4][c*4];
        unsigned w0 = Wm1p[c*4+0][u4], w1 = Wm1p[c*4+1][u4];
        unsigned w2 = Wm1p[c*4+2][u4], w3 = Wm1p[c*4+3][u4];
        m1lo = fmaf(v.x, lo16(w0), m1lo); m1hi = fmaf(v.x, hi16(w0), m1hi);
        m1lo = fmaf(v.y, lo16(w1), m1lo); m1hi = fmaf(v.y, hi16(w1), m1hi);
        m1lo = fmaf(v.z, lo16(w2), m1lo); m1hi = fmaf(v.z, hi16(w2), m1hi);
        m1lo = fmaf(v.w, lo16(w3), m1lo); m1hi = fmaf(v.w, hi16(w3), m1hi);
      }
    }
    asm volatile("" ::: "memory");
    if (tid == 0) {
      while (atomicAdd((unsigned*)(ws + psl + 256), 0u) != (unsigned)(t + 1))
        __builtin_amdgcn_s_sleep(2);
    }
    __syncthreads();
    if (tid < 256) {
      int p = tid >> 3, o = tid & 7;
      phbuf[p][(1-myM)*8 + o] = atomicAdd(ws + psl + tid, 0.0f);
    }
    __syncthreads();

    // P4 phase B: k = 32..47 in ascending order (deterministic across both blocks), then mlp2
    {
      float4 f0 = *(const float4*)&phbuf[p4][0];
      float4 f1 = *(const float4*)&phbuf[p4][4];
      float4 f2 = *(const float4*)&phbuf[p4][8];
      float4 f3 = *(const float4*)&phbuf[p4][12];
      float pv[16] = {f0.x,f0.y,f0.z,f0.w, f1.x,f1.y,f1.z,f1.w,
                      f2.x,f2.y,f2.z,f2.w, f3.x,f3.y,f3.z,f3.w};
      #pragma unroll
      for (int k = 0; k < 16; k++) {
        unsigned v = Wm1p[32 + k][u4];
        m1lo = fmaf(pv[k], lo16(v), m1lo);
        m1hi = fmaf(pv[k], hi16(v), m1hi);
      }
      m1lo = fmaxf(m1lo, 0.f); m1hi = fmaxf(m1hi, 0.f);
      // mlp2 via wave-synchronous LDS stage (2 writes + 16 broadcast b128)
      float* mb = uni + 2048 + p4*64;   // overlays dead gate half of uni (a1 is dead after P3)
      mb[u4]      = m1lo;
      mb[32 + u4] = m1hi;
      float acc = bm2l[u4];
      #pragma unroll
      for (int k4 = 0; k4 < 8; k4++) {
        float4 lo4 = *(const float4*)(mb + k4*4);
        float4 hi4 = *(const float4*)(mb + 32 + k4*4);
        unsigned v0 = Wm2p[k4*4+0][u4], v1 = Wm2p[k4*4+1][u4];
        unsigned v2 = Wm2p[k4*4+2][u4], v3 = Wm2p[k4*4+3][u4];
        acc = fmaf(lo4.x, lo16(v0), acc); acc = fmaf(hi4.x, hi16(v0), acc);
        acc = fmaf(lo4.y, lo16(v1), acc); acc = fmaf(hi4.y, hi16(v1), acc);
        acc = fmaf(lo4.z, lo16(v2), acc); acc = fmaf(hi4.z, hi16(v2), acc);
        acc = fmaf(lo4.w, lo16(v3), acc); acc = fmaf(hi4.w, hi16(v3), acc);
      }
      hbuf[p4][u4] = fmaxf(acc, 0.f);
    }
    __syncthreads();
  }
}

// ==================== mono fallback: 128 blocks (R4 kernel, verified) ====================
__global__ __launch_bounds__(1024, 1) void decoder_kernel_mono(
    const float* __restrict__ last_pos, const float* __restrict__ last_pos_rel,
    const float* __restrict__ hh, const float* __restrict__ ch,
    const int*  __restrict__ eg,
    const float* __restrict__ W_se, const float* __restrict__ b_se,
    const float* __restrict__ Wih, const float* __restrict__ Whh,
    const float* __restrict__ bih, const float* __restrict__ bhh,
    const float* __restrict__ W_hp, const float* __restrict__ b_hp,
    const float* __restrict__ W_pse, const float* __restrict__ b_pse,
    const float* __restrict__ W1a, const float* __restrict__ W2a,
    const float* __restrict__ W1b, const float* __restrict__ W2b,
    const float* __restrict__ W_m1, const float* __restrict__ b_m1,
    const float* __restrict__ W_m2, const float* __restrict__ b_m2,
    float* __restrict__ out)
{
  const int tid   = threadIdx.x;
  const int scn   = blockIdx.x;
  const int lane  = tid & 31;
  const int grp32 = tid >> 5;

  __shared__ __align__(16) float uni[4864];
  __shared__ __align__(16) unsigned W1p[2][16][GH];
  __shared__ __align__(16) float W2l[2][GH][GO];
  __shared__ __align__(16) float Wp1[2][2][GH];
  __shared__ __align__(16) float c1l[2][GH];
  __shared__ __align__(16) float hbuf[NP][HD];
  __shared__ __align__(16) float h2buf[NP][36];
  __shared__ __align__(16) float GS[2][5][GH];
  __shared__ __align__(16) float phbuf[NP][16];
  __shared__ __align__(16) unsigned Wm1p[48][32];
  __shared__ __align__(16) unsigned Wm2p[32][32];
  __shared__ float lpbuf[NP][2], rpbuf[NP][2], Whp[HD][2];
  __shared__ float bm1l[MD], bm2l[HD], bhp2[2];
  __shared__ unsigned bm[2][NP];
  __shared__ float invn[2][NP];
  __shared__ int gl[NP];

  const int myrow = tid & 127;
  const int pq4   = tid >> 7;
  float wrow[HD];
  #pragma unroll
  for (int c = 0; c < HD/4; c++) {
    float4 w = *(const float4*)(Whh + myrow*HD + c*4);
    wrow[c*4+0]=w.x; wrow[c*4+1]=w.y; wrow[c*4+2]=w.z; wrow[c*4+3]=w.w;
  }
  float wf0 = 0.f, wf1 = 0.f, bfr = bih[myrow] + bhh[myrow];
  #pragma unroll
  for (int e = 0; e < ED; e++) {
    float wv = Wih[myrow*ED + e];
    wf0 = fmaf(W_se[e],    wv, wf0);
    wf1 = fmaf(W_se[ED+e], wv, wf1);
    bfr = fmaf(b_se[e],    wv, bfr);
  }
  float creg = ch[(scn*NP + grp32)*HD + lane];
  hbuf[grp32][lane] = hh[(scn*NP + grp32)*HD + lane];

  if (tid < NP) {
    int gi = eg[scn*NP + tid];
    gl[tid] = gi;
    unsigned sm = 0;
    for (int j = 0; j < NP; j++) {
      int gj = eg[scn*NP + j];
      bool sj = (j == tid) || (gi == gj && gi != 0);
      sm |= ((unsigned)sj) << j;
    }
    unsigned dm = (~sm) | (1u << tid);
    bm[0][tid] = sm; bm[1][tid] = dm;
    invn[0][tid] = 1.0f/(float)__popc(sm);
    invn[1][tid] = 1.0f/(float)__popc(dm);
  }
  if (tid < 64) {
    int p = tid >> 1, k = tid & 1;
    lpbuf[p][k] = last_pos[(scn*NP+p)*2+k];
    rpbuf[p][k] = last_pos_rel[(scn*NP+p)*2+k];
    Whp[p][k]   = W_hp[tid];
    bm1l[tid]   = b_m1[tid];
  }
  if (tid < 32) bm2l[tid] = b_m2[tid];
  if (tid < 2)  bhp2[tid] = b_hp[tid];
  if (tid < 2*GH) {
    int m = tid / GH, d = tid % GH;
    const float* W1 = m ? W1b : W1a;
    float s0 = 0.f, s1 = 0.f, sc1 = 0.f;
    for (int e = 0; e < ED; e++) {
      float w = W1[e*GH + d];
      s0 += W_pse[e]*w; s1 += W_pse[ED+e]*w; sc1 += b_pse[e]*w;
    }
    Wp1[m][0][d] = s0; Wp1[m][1][d] = s1; c1l[m][d] = sc1;
  }
  {
    int u = tid;
    if (u < 2*GH*GO) {
      int m = u/(GH*GO), rest = u%(GH*GO);
      W2l[m][rest/GO][rest%GO] = (m ? W2b : W2a)[rest];
    }
    if (tid < 128) {
      int u2 = tid + 1024;
      int m = u2/(GH*GO), rest = u2%(GH*GO);
      W2l[m][rest/GO][rest%GO] = (m ? W2b : W2a)[rest];
    }
  }
  #pragma unroll
  for (int r = 0; r < 3; r++) {
    int u = tid + 1024*r;
    if (u < 2304) {
      int m = u/1152, rest = u%1152, k2 = rest/GH, d = rest%GH;
      const float* W1 = m ? W1b : W1a;
      W1p[m][k2][d] = rne16(W1[(ED+2*k2)*GH + d]) | (rne16(W1[(ED+2*k2+1)*GH + d]) << 16);
    }
  }
  #pragma unroll
  for (int r = 0; r < 2; r++) {
    int u = tid + 1024*r;
    if (u < 1536) {
      int k = u >> 5, uu = u & 31;
      Wm1p[k][uu] = rne16(W_m1[k*MD + uu]) | (rne16(W_m1[k*MD + 32 + uu]) << 16);
    }
  }
  {
    int k = tid >> 5, uu = tid & 31;
    Wm2p[k][uu] = rne16(W_m2[k*HD + uu]) | (rne16(W_m2[(k+32)*HD + uu]) << 16);
  }
  __syncthreads();

  for (int t = 0; t < TT; t++) {
    {
      float rG[4];
      #pragma unroll
      for (int pp2 = 0; pp2 < 4; pp2++) {
        int p = pq4*4 + pp2;
        float acc = fmaf(rpbuf[p][0], wf0, fmaf(rpbuf[p][1], wf1, bfr));
        #pragma unroll
        for (int c = 0; c < 8; c++) {
          float4 h4 = *(const float4*)&hbuf[p][c*4];
          acc = fmaf(h4.x, wrow[c*4+0], acc);
          acc = fmaf(h4.y, wrow[c*4+1], acc);
          acc = fmaf(h4.z, wrow[c*4+2], acc);
          acc = fmaf(h4.w, wrow[c*4+3], acc);
        }
        rG[pp2] = acc;
      }
      #pragma unroll
      for (int pp2 = 0; pp2 < 4; pp2++) uni[(pq4*4+pp2)*128 + myrow] = rG[pp2];
    }
    __syncthreads();
    {
      int p = grp32, n = lane;
      float gi_ = uni[p*128 + n];
      float gf_ = uni[p*128 + 32 + n];
      float gg_ = uni[p*128 + 64 + n];
      float go_ = uni[p*128 + 96 + n];
      float c2 = sigm(gf_)*creg + sigm(gi_)*tanhfast(gg_);
      creg = c2;
      float h2 = sigm(go_)*tanhfast(c2);
      h2buf[p][n] = h2;
      float r0 = h2 * Whp[n][0];
      float r1 = h2 * Whp[n][1];
      #pragma unroll
      for (int off = 1; off < 32; off <<= 1) {
        r0 += __shfl_xor(r0, off, 32);
        r1 += __shfl_xor(r1, off, 32);
      }
      r0 += bhp2[0]; r1 += bhp2[1];
      if (n == 0) {
        out[t*NB*2 + (scn*NP+p)*2 + 0] = r0;
        out[t*NB*2 + (scn*NP+p)*2 + 1] = r1;
        rpbuf[p][0] = r0;  rpbuf[p][1] = r1;
        lpbuf[p][0] += r0; lpbuf[p][1] += r1;
      }
    }
    __syncthreads();
    {
      const int j = lane;
      float lpj0 = lpbuf[j][0], lpj1 = lpbuf[j][1];
      float h2row[HD];
      #pragma unroll
      for (int c = 0; c < 8; c++) {
        float4 v = *(const float4*)&h2buf[j][c*4];
        h2row[c*4+0]=v.x; h2row[c*4+1]=v.y; h2row[c*4+2]=v.z; h2row[c*4+3]=v.w;
      }
      #pragma unroll
      for (int r = 0; r < 5; r++) {
        int rest = grp32 + 32*r;
        if (rest < 144) {
          int m = rest >= 72 ? 1 : 0;
          int d = rest - 72*m;
          float pp_ = fmaf(lpj0, Wp1[m][0][d], lpj1*Wp1[m][1][d]);
          float av = pp_;
          #pragma unroll
          for (int k2 = 0; k2 < 16; k2++) {
            unsigned v = W1p[m][k2][d];
            av = fmaf(h2row[2*k2], lo16(v), av);
            av = fmaf(h2row[2*k2+1], hi16(v), av);
          }
          uni[m*2432 + j*76 + d] = av;
          int gj = gl[j];
          float tot = av;
          float s1 = (gj==1)?av:0.f, s2=(gj==2)?av:0.f, s3=(gj==3)?av:0.f, s4=(gj==4)?av:0.f;
          #pragma unroll
          for (int off = 1; off < 32; off <<= 1) {
            tot += __shfl_xor(tot, off, 32);
            s1 += __shfl_xor(s1, off, 32);
            s2 += __shfl_xor(s2, off, 32);
            s3 += __shfl_xor(s3, off, 32);
            s4 += __shfl_xor(s4, off, 32);
          }
          if (j < 5) {
            float v2;
            if (m == 0) v2 = (j==0)?tot:((j==1)?s1:((j==2)?s2:((j==3)?s3:s4)));
            else        v2 = (j==0)?tot:((j==1)?tot-s1:((j==2)?tot-s2:((j==3)?tot-s3:tot-s4)));
            GS[m][j][d] = v2;
          }
        }
      }
    }
    __syncthreads();
    {
      const int j   = lane;
      const int m   = tid >> 9;
      const int sub = (tid >> 5) & 15;
      const float* am = uni + m*2432;
      int   I2[2] = {sub, sub + 16};
      const float *P0[2], *P1[2];
      float C0[2], C1[2], NL0[2], NL1[2];
      bool  MIJ[2], DIAG[2];
      v2f qv[2][4];
      #pragma unroll
      for (int r = 0; r < 2; r++) {
        int i = I2[r];
        unsigned bmv = bm[m][i];
        bool mij = (bmv >> j) & 1u;
        bool diag = (j == i);
        int gi = gl[i];
        float in_ = invn[m][i];
        const float *p0, *p1; float c0, c1c;
        if (diag) {
          if (m == 0) { p0 = gi ? &GS[0][gi][0] : (am + i*76); c0 = in_; p1 = am + i*76; c1c = 0.f; }
          else        { p0 = &GS[1][gi][0];                    c0 = in_; p1 = am + i*76; c1c = gi ? in_ : 0.f; }
        } else if (mij) { p0 = am + j*76; c0 = 0.5f; p1 = am + i*76; c1c = 0.5f; }
        else            { p0 = am + j*76; c0 = 1.0f; p1 = am + j*76; c1c = 0.f; }
        P0[r]=p0; P1[r]=p1; C0[r]=c0; C1[r]=c1c; MIJ[r]=mij; DIAG[r]=diag;
        NL0[r] = -lpbuf[i][0]; NL1[r] = -lpbuf[i][1];
        #pragma unroll
        for (int h = 0; h < 4; h++) qv[r][h] = (v2f){0.f, 0.f};
      }
      for (int d4 = 0; d4 < GH/4; d4++) {
        float4 c14 = *(const float4*)&c1l[m][d4*4];
        float4 w04 = *(const float4*)&Wp1[m][0][d4*4];
        float4 w14 = *(const float4*)&Wp1[m][1][d4*4];
        float4 vaS = *(const float4*)(am + j*76 + d4*4);
        float4 va0 = vaS, va1 = vaS;
        if (DIAG[0]) va0 = *(const float4*)(P0[0] + d4*4);
        if (DIAG[1]) va1 = *(const float4*)(P0[1] + d4*4);
        float4 vb0 = *(const float4*)(P1[0] + d4*4);
        float4 vb1 = *(const float4*)(P1[1] + d4*4);
        float e0x = fmaf(NL1[0], w14.x, fmaf(NL0[0], w04.x, c14.x));
        float e0y = fmaf(NL1[0], w14.y, fmaf(NL0[0], w04.y, c14.y));
        float e0z = fmaf(NL1[0], w14.z, fmaf(NL0[0], w04.z, c14.z));
        float e0w = fmaf(NL1[0], w14.w, fmaf(NL0[0], w04.w, c14.w));
        float e1x = fmaf(NL1[1], w14.x, fmaf(NL0[1], w04.x, c14.x));
        float e1y = fmaf(NL1[1], w14.y, fmaf(NL0[1], w04.y, c14.y));
        float e1z = fmaf(NL1[1], w14.z, fmaf(NL0[1], w04.z, c14.z));
        float e1w = fmaf(NL1[1], w14.w, fmaf(NL0[1], w04.w, c14.w));
        float tv0[4], tv1[4];
        tv0[0] = fmaxf(fmaf(C0[0], va0.x, fmaf(C1[0], vb0.x, e0x)), 0.f);
        tv0[1] = fmaxf(fmaf(C0[0], va0.y, fmaf(C1[0], vb0.y, e0y)), 0.f);
        tv0[2] = fmaxf(fmaf(C0[0], va0.z, fmaf(C1[0], vb0.z, e0z)), 0.f);
        tv0[3] = fmaxf(fmaf(C0[0], va0.w, fmaf(C1[0], vb0.w, e0w)), 0.f);
        tv1[0] = fmaxf(fmaf(C0[1], va1.x, fmaf(C1[1], vb1.x, e1x)), 0.f);
        tv1[1] = fmaxf(fmaf(C0[1], va1.y, fmaf(C1[1], vb1.y, e1y)), 0.f);
        tv1[2] = fmaxf(fmaf(C0[1], va1.z, fmaf(C1[1], vb1.z, e1z)), 0.f);
        tv1[3] = fmaxf(fmaf(C0[1], va1.w, fmaf(C1[1], vb1.w, e1w)), 0.f);
        #pragma unroll
        for (int k = 0; k < 4; k++) {
          const v2f* w2p = (const v2f*)&W2l[m][d4*4+k][0];
          v2f wA = w2p[0], wB = w2p[1], wC = w2p[2], wD = w2p[3];
          v2f t0 = {tv0[k], tv0[k]};
          qv[0][0] += t0*wA; qv[0][1] += t0*wB; qv[0][2] += t0*wC; qv[0][3] += t0*wD;
          v2f t1 = {tv1[k], tv1[k]};
          qv[1][0] += t1*wA; qv[1][1] += t1*wB; qv[1][2] += t1*wC; qv[1][3] += t1*wD;
        }
      }
      #pragma unroll
      for (int r = 0; r < 2; r++) {
        float q[8];
        #pragma unroll
        for (int h = 0; h < 4; h++) { q[2*h] = qv[r][h][0]; q[2*h+1] = qv[r][h][1]; }
        float sq[8];
        #pragma unroll
        for (int o = 0; o < 8; o++) sq[o] = MIJ[r] ? q[o] : 0.f;
        #pragma unroll
        for (int off = 1; off < 32; off <<= 1) {
          #pragma unroll
          for (int o = 0; o < 8; o++) sq[o] += __shfl_xor(sq[o], off, 32);
        }
        float qd[8];
        #pragma unroll
        for (int o = 0; o < 8; o++) qd[o] = __shfl(q[o], I2[r], 32);
        float in_ = invn[m][I2[r]];
        float F[8];
        if (DIAG[r]) {
          #pragma unroll
          for (int o = 0; o < 8; o++) F[o] = fmaxf(sq[o]*in_, 0.f);
        } else {
          float scl = MIJ[r] ? 0.5f : 1.0f;
          #pragma unroll
          for (int o = 0; o < 8; o++)
            F[o] = fmaxf((q[o] + (MIJ[r] ? qd[o] : 0.f))*scl, 0.f);
        }
        #pragma unroll
        for (int off = 1; off < 32; off <<= 1) {
          #pragma unroll
          for (int o = 0; o < 8; o++) F[o] = fmaxf(F[o], __shfl_xor(F[o], off, 32));
        }
        if (j == 0) {
          #pragma unroll
          for (int o = 0; o < 8; o++) phbuf[I2[r]][m*GO + o] = F[o];
        }
      }
    }
    __syncthreads();
    {
      int p = grp32, u = lane;
      float in48[48];
      #pragma unroll
      for (int c = 0; c < 8; c++) {
        float4 v = *(const float4*)&h2buf[p][c*4];
        in48[c*4+0]=v.x; in48[c*4+1]=v.y; in48[c*4+2]=v.z; in48[c*4+3]=v.w;
      }
      #pragma unroll
      for (int c = 0; c < 4; c++) {
        float4 v = *(const float4*)&phbuf[p][c*4];
        in48[32+c*4+0]=v.x; in48[32+c*4+1]=v.y; in48[32+c*4+2]=v.z; in48[32+c*4+3]=v.w;
      }
      float m1lo = bm1l[u], m1hi = bm1l[32 + u];
      #pragma unroll
      for (int k = 0; k < 48; k++) {
        unsigned v = Wm1p[k][u];
        m1lo = fmaf(in48[k], lo16(v), m1lo);
        m1hi = fmaf(in48[k], hi16(v), m1hi);
      }
      m1lo = fmaxf(m1lo, 0.f); m1hi = fmaxf(m1hi, 0.f);
      float acc = bm2l[u];
      #pragma unroll
      for (int k = 0; k < 32; k++) {
        unsigned v = Wm2p[k][u];
        acc = fmaf(__shfl(m1lo, k, 32), lo16(v), acc);
        acc = fmaf(__shfl(m1hi, k, 32), hi16(v), acc);
      }
      hbuf[p][u] = fmaxf(acc, 0.f);
    }
    __syncthreads();
  }
}

extern "C" void kernel_launch(void* const* d_in, const int* in_sizes, int n_in,
                              void* d_out, int out_size, void* d_ws, size_t ws_size,
                              hipStream_t stream) {
  (void)in_sizes; (void)n_in; (void)out_size;
  const float* last_pos     = (const float*)d_in[0];
  const float* last_pos_rel = (const float*)d_in[1];
  const float* hh           = (const float*)d_in[2];
  const float* ch           = (const float*)d_in[3];
  const int*  eg            = (const int*) d_in[5];
  const float* W_se  = (const float*)d_in[6];
  const float* b_se  = (const float*)d_in[7];
  const float* Wih   = (const float*)d_in[8];
  const float* Whh   = (const float*)d_in[9];
  const float* bih   = (const float*)d_in[10];
  const float* bhh   = (const float*)d_in[11];
  const float* W_hp  = (const float*)d_in[12];
  const float* b_hp  = (const float*)d_in[13];
  const float* W_pse = (const float*)d_in[14];
  const float* b_pse = (const float*)d_in[15];
  const float* W1a   = (const float*)d_in[16];
  const float* W2a   = (const float*)d_in[17];
  const float* W1b   = (const float*)d_in[18];
  const float* W2b   = (const float*)d_in[19];
  const float* W_m1  = (const float*)d_in[20];
  const float* b_m1  = (const float*)d_in[21];
  const float* W_m2  = (const float*)d_in[22];
  const float* b_m2  = (const float*)d_in[23];
  float* out = (float*)d_out;

  if (ws_size >= (size_t)WS_NEED) {
    decoder_kernel_split<<<2*NS, 1024, 0, stream>>>(
        last_pos, last_pos_rel, hh, ch, eg,
        W_se, b_se, Wih, Whh, bih, bhh, W_hp, b_hp, W_pse, b_pse,
        W1a, W2a, W1b, W2b, W_m1, b_m1, W_m2, b_m2, out, (float*)d_ws);
  } else {
    decoder_kernel_mono<<<NS, 1024, 0, stream>>>(
        last_pos, last_pos_rel, hh, ch, eg,
        W_se, b_se, Wih, Whh, bih, bhh, W_hp, b_hp, W_pse, b_pse,
        W1a, W2a, W1b, W2b, W_m1, b_m1, W_m2, b_m2, out);
  }
}

// Round 13
// 233.819 us; speedup vs baseline: 1.0348x; 1.0055x over previous
//
#include <hip/hip_runtime.h>

#define NS 128
#define NP 32
#define HD 32
#define ED 16
#define GH 72
#define GO 8
#define MD 64
#define TT 8
#define NB (NS*NP)
#define EW 76

#define SLOT 272   // floats per slot: 256 data + flag + pad
// 256 blocks x 2 parity slots
#define WS_NEED (256*2*SLOT*4)

typedef float v2f __attribute__((ext_vector_type(2)));

__device__ __forceinline__ float sigm(float x){ return 1.0f/(1.0f+__expf(-x)); }
__device__ __forceinline__ float tanhfast(float x){ return 1.0f - 2.0f/(__expf(2.0f*x)+1.0f); }
__device__ __forceinline__ unsigned rne16(float f){
  unsigned u = __float_as_uint(f);
  u += 0x7fffu + ((u>>16)&1u);
  return u>>16;
}
__device__ __forceinline__ float lo16(unsigned v){ return __uint_as_float(v<<16); }
__device__ __forceinline__ float hi16(unsigned v){ return __uint_as_float(v & 0xffff0000u); }
// unpack a bf16-pair dword to v2f {lo,hi}
__device__ __forceinline__ v2f bp2(unsigned v){ return (v2f){lo16(v), hi16(v)}; }
// DPP cross-lane move (VALU pipe).
// 0xB1 = quad_perm xor1, 0x4E = quad_perm xor2,
// 0x141 = row_half_mirror (8-sum after xor1/xor2), 0x140 = row_mirror (16-sum).
template<int C>
__device__ __forceinline__ float dppx(float x){
  return __int_as_float(__builtin_amdgcn_update_dpp(0, __float_as_int(x), C, 0xF, 0xF, true));
}
#define XOR1 0xB1
#define XOR2 0x4E
#define HMIR 0x141
#define MIR  0x140
// full 32-lane sum: 4 DPP levels + one DS shfl for the 16-offset
__device__ __forceinline__ float wsum32(float v){
  v += dppx<XOR1>(v);
  v += dppx<XOR2>(v);
  v += dppx<HMIR>(v);
  v += dppx<MIR >(v);
  v += __shfl_xor(v, 16, 32);
  return v;
}

// ==================== split kernel: 256 blocks, (scene, m) per block ====================
__global__ __launch_bounds__(1024, 1) void decoder_kernel_split(
    const float* __restrict__ last_pos, const float* __restrict__ last_pos_rel,
    const float* __restrict__ hh, const float* __restrict__ ch,
    const int*  __restrict__ eg,
    const float* __restrict__ W_se, const float* __restrict__ b_se,
    const float* __restrict__ Wih, const float* __restrict__ Whh,
    const float* __restrict__ bih, const float* __restrict__ bhh,
    const float* __restrict__ W_hp, const float* __restrict__ b_hp,
    const float* __restrict__ W_pse, const float* __restrict__ b_pse,
    const float* __restrict__ W1a, const float* __restrict__ W2a,
    const float* __restrict__ W1b, const float* __restrict__ W2b,
    const float* __restrict__ W_m1, const float* __restrict__ b_m1,
    const float* __restrict__ W_m2, const float* __restrict__ b_m2,
    float* __restrict__ out, float* __restrict__ ws)
{
  const int tid   = threadIdx.x;
  const int scn   = blockIdx.x >> 1;
  const int myM   = blockIdx.x & 1;
  const int lane  = tid & 31;
  const int grp32 = tid >> 5;      // 0..31

  // uni overlays: G[32][128] gate staging (16 KB) <-> a1[32][76] (9.7 KB) <-> m1-stage (P4, uni+2048)
  __shared__ __align__(16) float uni[4096];
  __shared__ __align__(16) unsigned W1pT[GH][16];  // own m, bf16 pairs, TRANSPOSED (row d = 16 dwords)
  __shared__ __align__(16) float Wp1[2][GH];       // own m
  __shared__ __align__(16) float c1l[GH];          // own m
  __shared__ __align__(16) float ebuf[NP*EW];      // e[i][d] = c1 - lp[i].Wp1  (P3 coef precompute)
  __shared__ __align__(16) float hbuf[NP][HD];
  __shared__ __align__(16) float h2buf[NP][36];
  __shared__ __align__(16) float GS[5][GH];        // own m
  __shared__ __align__(16) float phbuf[NP][16];
  __shared__ __align__(16) unsigned Wm1p[48][32];
  __shared__ __align__(16) unsigned Wm2p[32][32];
  __shared__ float lpbuf[NP][2], rpbuf[NP][2], Whp[HD][2];
  __shared__ float bm1l[MD], bm2l[HD], bhp2[2];
  __shared__ unsigned bm[NP];
  __shared__ unsigned gmsk[5];                     // group membership masks (g=0 -> all)
  __shared__ float invn[NP];
  __shared__ int gl[NP];

  float* const a1 = uni;   // [32][76]

  const int mybase = (scn*2 + myM)*2;       // slot-pair index (x SLOT)
  const int pbase  = (scn*2 + 1 - myM)*2;

  // ---------- persistent per-thread LSTM row weights (global read ONCE) ----------
  const int myrow = tid & 127;
  const int pq4   = tid >> 7;
  float wrow[HD];
  #pragma unroll
  for (int c = 0; c < HD/4; c++) {
    float4 w = *(const float4*)(Whh + myrow*HD + c*4);
    wrow[c*4+0]=w.x; wrow[c*4+1]=w.y; wrow[c*4+2]=w.z; wrow[c*4+3]=w.w;
  }
  float wf0 = 0.f, wf1 = 0.f, bfr = bih[myrow] + bhh[myrow];
  #pragma unroll
  for (int e = 0; e < ED; e++) {
    float wv = Wih[myrow*ED + e];
    wf0 = fmaf(W_se[e],    wv, wf0);
    wf1 = fmaf(W_se[ED+e], wv, wf1);
    bfr = fmaf(b_se[e],    wv, bfr);
  }

  float creg = ch[(scn*NP + grp32)*HD + lane];
  hbuf[grp32][lane] = hh[(scn*NP + grp32)*HD + lane];

  // ---------- setup ----------
  if (tid < NP) {
    int gi = eg[scn*NP + tid];
    gl[tid] = gi;
    unsigned sm = 0;
    for (int j = 0; j < NP; j++) {
      int gj = eg[scn*NP + j];
      bool sj = (j == tid) || (gi == gj && gi != 0);
      sm |= ((unsigned)sj) << j;
    }
    unsigned mk = myM ? ((~sm) | (1u << tid)) : sm;
    bm[tid] = mk;
    invn[tid] = 1.0f/(float)__popc(mk);
  }
  if (tid < 5) {       // membership mask per group id
    unsigned mv = 0;
    for (int j = 0; j < NP; j++) if (eg[scn*NP + j] == tid) mv |= (1u << j);
    gmsk[tid] = (tid == 0) ? 0xFFFFFFFFu : mv;
  }
  if (tid < 64) {
    int p = tid >> 1, k = tid & 1;
    lpbuf[p][k] = last_pos[(scn*NP+p)*2+k];
    rpbuf[p][k] = last_pos_rel[(scn*NP+p)*2+k];
    Whp[p][k]   = W_hp[tid];
    bm1l[tid]   = b_m1[tid];
  }
  if (tid < 32) bm2l[tid] = b_m2[tid];
  if (tid < 2)  bhp2[tid] = b_hp[tid];
  const float* W1my = myM ? W1b : W1a;
  const float* W2g  = myM ? W2b : W2a;    // W2 read from GLOBAL with uniform index -> s_load, off the DS pipe
  if (tid < GH) {   // folded Wp1 = W_pse@W1[:16], c1 = b_pse@W1[:16] (own m)
    int d = tid;
    float s0 = 0.f, s1 = 0.f, sc1 = 0.f;
    for (int e = 0; e < ED; e++) {
      float w = W1my[e*GH + d];
      s0  += W_pse[e]    * w;
      s1  += W_pse[ED+e] * w;
      sc1 += b_pse[e]    * w;
    }
    Wp1[0][d] = s0; Wp1[1][d] = s1; c1l[d] = sc1;
  }
  #pragma unroll
  for (int r = 0; r < 2; r++) {  // W1pT own m, packed bf16, transposed (1152 > 1024: TWO passes)
    int u = tid + 1024*r;
    if (u < 16*GH) {
      int k2 = u/GH, d = u%GH;
      unsigned lo = rne16(W1my[(ED+2*k2  )*GH + d]);
      unsigned hi = rne16(W1my[(ED+2*k2+1)*GH + d]);
      W1pT[d][k2] = lo | (hi << 16);
    }
  }
  #pragma unroll
  for (int r = 0; r < 2; r++) {   // Wm1p packed bf16 (1536)
    int u = tid + 1024*r;
    if (u < 1536) {
      int k = u >> 5, uu = u & 31;
      Wm1p[k][uu] = rne16(W_m1[k*MD + uu]) | (rne16(W_m1[k*MD + 32 + uu]) << 16);
    }
  }
  {  // Wm2p packed bf16 (1024)
    int k = tid >> 5, uu = tid & 31;
    Wm2p[k][uu] = rne16(W_m2[k*HD + uu]) | (rne16(W_m2[(k+32)*HD + uu]) << 16);
  }
  __syncthreads();

  // ---------------- time steps ----------------
  for (int t = 0; t < TT; t++) {
    // P1a: gates[p][myrow] for 4 peds (redundant in both blocks; deterministic)
    // b128-broadcast hbuf reads (wave-uniform addr -> conflict-free)
    {
      float rG[4];
      #pragma unroll
      for (int pp2 = 0; pp2 < 4; pp2++) {
        int p = pq4*4 + pp2;
        float acc = fmaf(rpbuf[p][0], wf0, fmaf(rpbuf[p][1], wf1, bfr));
        #pragma unroll
        for (int c = 0; c < 8; c++) {
          float4 h4 = *(const float4*)&hbuf[p][c*4];
          acc = fmaf(h4.x, wrow[c*4+0], acc);
          acc = fmaf(h4.y, wrow[c*4+1], acc);
          acc = fmaf(h4.z, wrow[c*4+2], acc);
          acc = fmaf(h4.w, wrow[c*4+3], acc);
        }
        rG[pp2] = acc;
      }
      #pragma unroll
      for (int pp2 = 0; pp2 < 4; pp2++) uni[(pq4*4+pp2)*128 + myrow] = rG[pp2];
    }
    __syncthreads();

    // P1b: activations, c/h2 update; rel_pos reduction; out store (m=0 block only)
    {
      int p = grp32, n = lane;
      float gi_ = uni[p*128 +       n];
      float gf_ = uni[p*128 +  32 + n];
      float gg_ = uni[p*128 +  64 + n];
      float go_ = uni[p*128 +  96 + n];
      float c2 = sigm(gf_)*creg + sigm(gi_)*tanhfast(gg_);
      creg = c2;
      float h2 = sigm(go_)*tanhfast(c2);
      h2buf[p][n] = h2;
      float r0 = h2 * Whp[n][0];
      float r1 = h2 * Whp[n][1];
      // full reduction tree on VALU via DPP, one DS shfl for the 16-offset
      r0 += dppx<XOR1>(r0); r1 += dppx<XOR1>(r1);
      r0 += dppx<XOR2>(r0); r1 += dppx<XOR2>(r1);
      r0 += dppx<HMIR>(r0); r1 += dppx<HMIR>(r1);
      r0 += dppx<MIR >(r0); r1 += dppx<MIR >(r1);
      r0 += __shfl_xor(r0, 16, 32);
      r1 += __shfl_xor(r1, 16, 32);
      r0 += bhp2[0]; r1 += bhp2[1];
      if (n == 0) {
        if (myM == 0) {
          out[t*NB*2 + (scn*NP+p)*2 + 0] = r0;
          out[t*NB*2 + (scn*NP+p)*2 + 1] = r1;
        }
        rpbuf[p][0] = r0;  rpbuf[p][1] = r1;
        lpbuf[p][0] += r0; lpbuf[p][1] += r1;
      }
    }
    __syncthreads();

    // P2: a1[j][d] + GS group sums via DPP trees + ebuf precompute
    // packed v2f accumulation (v_pk_fma_f32) -- bf16 pair {lo,hi} x adjacent h2 pair
    {
      const int j = lane;
      float lpj0 = lpbuf[j][0], lpj1 = lpbuf[j][1];
      const int gj = gl[j];
      v2f h2p[16];   // adjacent pairs of h2row
      #pragma unroll
      for (int c = 0; c < 8; c++) {
        float4 v = *(const float4*)&h2buf[j][c*4];
        h2p[c*2+0] = (v2f){v.x, v.y};
        h2p[c*2+1] = (v2f){v.z, v.w};
      }
      #pragma unroll
      for (int r = 0; r < 3; r++) {
        int d = grp32 + 32*r;
        if (d < GH) {
          v2f av2 = (v2f){0.f, 0.f};
          #pragma unroll
          for (int k8 = 0; k8 < 4; k8++) {   // 4 half-wave-uniform b128, packed MACs
            uint4 w4 = *(const uint4*)&W1pT[d][k8*4];
            av2 += h2p[k8*4+0]*bp2(w4.x);
            av2 += h2p[k8*4+1]*bp2(w4.y);
            av2 += h2p[k8*4+2]*bp2(w4.z);
            av2 += h2p[k8*4+3]*bp2(w4.w);
          }
          float av = fmaf(lpj0, Wp1[0][d], lpj1*Wp1[1][d]) + (av2[0] + av2[1]);
          a1[j*EW + d] = av;
          // GS via DPP trees (VALU), inline
          float tot = wsum32(av);
          float s1 = wsum32((gj==1) ? av : 0.f);
          float s2 = wsum32((gj==2) ? av : 0.f);
          float s3 = wsum32((gj==3) ? av : 0.f);
          float s4 = wsum32((gj==4) ? av : 0.f);
          if (j < 5) {
            float v2;
            if (myM == 0) v2 = (j==0)?tot:((j==1)?s1:((j==2)?s2:((j==3)?s3:s4)));
            else          v2 = (j==0)?tot:((j==1)?tot-s1:((j==2)?tot-s2:((j==3)?tot-s3:tot-s4)));
            GS[j][d] = v2;
          }
        }
      }
      // e[i][d] precompute
      #pragma unroll
      for (int ii = 0; ii < 3; ii++) {
        int idx = tid + 1024*ii;
        if (idx < NP*GH) {
          int d = idx >> 5, i2 = idx & 31;
          ebuf[i2*EW + d] = fmaf(-lpbuf[i2][1], Wp1[1][d],
                            fmaf(-lpbuf[i2][0], Wp1[0][d], c1l[d]));
        }
      }
    }
    __syncthreads();

    // P3: pool (own m). One task per thread: i = grp32, j = lane.
    // Unroll-by-2 for ILP + packed-fp32 tv.
    {
      const int j = lane, i = grp32;
      unsigned bmv = bm[i];
      bool mij = (bmv >> j) & 1u;
      bool diag = (j == i);
      int gi = gl[i];
      float in_ = invn[i];
      const float *p0, *p1; float c0, c1c;
      if (diag) {
        if (myM == 0) { p0 = gi ? &GS[gi][0] : (a1 + i*EW); c0 = in_; p1 = a1 + i*EW; c1c = 0.f; }
        else          { p0 = &GS[gi][0];                    c0 = in_; p1 = a1 + i*EW; c1c = gi ? in_ : 0.f; }
      } else if (mij) { p0 = a1 + j*EW; c0 = 0.5f; p1 = a1 + i*EW; c1c = 0.5f; }
      else            { p0 = a1 + j*EW; c0 = 1.0f; p1 = a1 + j*EW; c1c = 0.f; }
      const float* erow = ebuf + i*EW;
      const v2f c0v = (v2f){c0, c0};
      const v2f c1v = (v2f){c1c, c1c};
      v2f qv[4];
      #pragma unroll
      for (int h = 0; h < 4; h++) qv[h] = (v2f){0.f, 0.f};
      #pragma unroll 2
      for (int d4 = 0; d4 < GH/4; d4++) {
        float4 e4 = *(const float4*)(erow + d4*4);
        float4 va = diag ? *(const float4*)(p0 + d4*4)
                         : *(const float4*)(a1 + j*EW + d4*4);
        float4 vb = *(const float4*)(p1 + d4*4);
        // packed tv: t = relu(c0*va + (c1c*vb + e)) on v_pk_fma_f32/v_pk_max_f32
        v2f e01 = (v2f){e4.x, e4.y}, e23 = (v2f){e4.z, e4.w};
        v2f va01 = (v2f){va.x, va.y}, va23 = (v2f){va.z, va.w};
        v2f vb01 = (v2f){vb.x, vb.y}, vb23 = (v2f){vb.z, vb.w};
        v2f u01 = c1v*vb01 + e01;
        v2f u23 = c1v*vb23 + e23;
        v2f t01 = c0v*va01 + u01;
        v2f t23 = c0v*va23 + u23;
        t01 = (v2f){fmaxf(t01[0], 0.f), fmaxf(t01[1], 0.f)};
        t23 = (v2f){fmaxf(t23[0], 0.f), fmaxf(t23[1], 0.f)};
        float tv[4] = {t01[0], t01[1], t23[0], t23[1]};
        #pragma unroll
        for (int k = 0; k < 4; k++) {
          // uniform global reads -> s_load into SGPRs, zero DS traffic
          const float* wr = W2g + (d4*4+k)*GO;
          v2f wA = {wr[0], wr[1]}, wB = {wr[2], wr[3]};
          v2f wC = {wr[4], wr[5]}, wD = {wr[6], wr[7]};
          v2f tk = {tv[k], tv[k]};
          qv[0] += tk*wA; qv[1] += tk*wB; qv[2] += tk*wC; qv[3] += tk*wD;
        }
      }
      float q[8];
      #pragma unroll
      for (int h = 0; h < 4; h++) { q[2*h] = qv[h][0]; q[2*h+1] = qv[h][1]; }
      float sq[8];
      #pragma unroll
      for (int o = 0; o < 8; o++) sq[o] = mij ? q[o] : 0.f;
      // sum tree via DPP + single DS shfl for the 16-offset
      #pragma unroll
      for (int o = 0; o < 8; o++) sq[o] += dppx<XOR1>(sq[o]);
      #pragma unroll
      for (int o = 0; o < 8; o++) sq[o] += dppx<XOR2>(sq[o]);
      #pragma unroll
      for (int o = 0; o < 8; o++) sq[o] += dppx<HMIR>(sq[o]);
      #pragma unroll
      for (int o = 0; o < 8; o++) sq[o] += dppx<MIR >(sq[o]);
      #pragma unroll
      for (int o = 0; o < 8; o++) sq[o] += __shfl_xor(sq[o], 16, 32);
      float qd[8];
      #pragma unroll
      for (int o = 0; o < 8; o++) qd[o] = __shfl(q[o], i, 32);
      float F[8];
      if (diag) {
        #pragma unroll
        for (int o = 0; o < 8; o++) F[o] = fmaxf(sq[o]*in_, 0.f);
      } else {
        float scl = mij ? 0.5f : 1.0f;
        #pragma unroll
        for (int o = 0; o < 8; o++)
          F[o] = fmaxf((q[o] + (mij ? qd[o] : 0.f))*scl, 0.f);
      }
      // max tree via DPP + single DS shfl (max is order-independent)
      #pragma unroll
      for (int o = 0; o < 8; o++) F[o] = fmaxf(F[o], dppx<XOR1>(F[o]));
      #pragma unroll
      for (int o = 0; o < 8; o++) F[o] = fmaxf(F[o], dppx<XOR2>(F[o]));
      #pragma unroll
      for (int o = 0; o < 8; o++) F[o] = fmaxf(F[o], dppx<HMIR>(F[o]));
      #pragma unroll
      for (int o = 0; o < 8; o++) F[o] = fmaxf(F[o], dppx<MIR >(F[o]));
      #pragma unroll
      for (int o = 0; o < 8; o++) F[o] = fmaxf(F[o], __shfl_xor(F[o], 16, 32));
      if (j == 0) {
        // write own pooled half straight to ws from P3 tail
        const int slw = (mybase + (t & 1))*SLOT;
        #pragma unroll
        for (int o = 0; o < 8; o++) {
          phbuf[i][myM*GO + o] = F[o];
          atomicExch(ws + slw + i*8 + o, F[o]);
        }
      }
    }
    __syncthreads();   // drains vmcnt in every wave -> pooled data globally visible

    // ---- exchange (double-buffered by t parity), overlapped with mlp1 h2-part ----
    const int sl  = (mybase + (t & 1))*SLOT;
    const int psl = (pbase  + (t & 1))*SLOT;
    if (tid == 0) atomicExch((unsigned*)(ws + sl + 256), (unsigned)(t + 1));
    asm volatile("" ::: "memory");
    // P4 phase A: mlp1 partial, k = 0..31 (h2 part only -> summation order identical in both blocks)
    const int p4 = grp32, u4 = lane;
    float m1lo = bm1l[u4], m1hi = bm1l[32 + u4];
    {
      #pragma unroll
      for (int c = 0; c < 8; c++) {
        float4 v = *(const float4*)&h2buf[p4][c*4];
        unsigned w0 = Wm1p[c*4+0][u4], w1 = Wm1p[c*4+1][u4];
        unsigned w2 = Wm1p[c*4+2][u4], w3 = Wm1p[c*4+3][u4];
        m1lo = fmaf(v.x, lo16(w0), m1lo); m1hi = fmaf(v.x, hi16(w0), m1hi);
        m1lo = fmaf(v.y, lo16(w1), m1lo); m1hi = fmaf(v.y, hi16(w1), m1hi);
        m1lo = fmaf(v.z, lo16(w2), m1lo); m1hi = fmaf(v.z, hi16(w2), m1hi);
        m1lo = fmaf(v.w, lo16(w3), m1lo); m1hi = fmaf(v.w, hi16(w3), m1hi);
      }
    }
    asm volatile("" ::: "memory");
    if (tid == 0) {
      while (atomicAdd((unsigned*)(ws + psl + 256), 0u) != (unsigned)(t + 1))
        __builtin_amdgcn_s_sleep(2);
    }
    __syncthreads();
    if (tid < 256) {
      int p = tid >> 3, o = tid & 7;
      phbuf[p][(1-myM)*8 + o] = atomicAdd(ws + psl + tid, 0.0f);
    }
    __syncthreads();

    // P4 phase B: k = 32..47 in ascending order (deterministic across both blocks), then mlp2
    {
      float4 f0 = *(const float4*)&phbuf[p4][0];
      float4 f1 = *(const float4*)&phbuf[p4][4];
      float4 f2 = *(const float4*)&phbuf[p4][8];
      float4 f3 = *(const float4*)&phbuf[p4][12];
      float pv[16] = {f0.x,f0.y,f0.z,f0.w, f1.x,f1.y,f1.z,f1.w,
                      f2.x,f2.y,f2.z,f2.w, f3.x,f3.y,f3.z,f3.w};
      #pragma unroll
      for (int k = 0; k < 16; k++) {
        unsigned v = Wm1p[32 + k][u4];
        m1lo = fmaf(pv[k], lo16(v), m1lo);
        m1hi = fmaf(pv[k], hi16(v), m1hi);
      }
      m1lo = fmaxf(m1lo, 0.f); m1hi = fmaxf(m1hi, 0.f);
      // mlp2 via wave-synchronous LDS stage (2 writes + 16 broadcast b128)
      // packed v2f accumulation -- {m1lo_k, m1hi_k} x {lo16(w), hi16(w)} into one 2-wide acc
      float* mb = uni + 2048 + p4*64;   // overlays dead gate half of uni (a1 is dead after P3)
      mb[u4]      = m1lo;
      mb[32 + u4] = m1hi;
      v2f acc2 = (v2f){bm2l[u4], 0.f};
      #pragma unroll
      for (int k4 = 0; k4 < 8; k4++) {
        float4 lo4 = *(const float4*)(mb + k4*4);
        float4 hi4 = *(const float4*)(mb + 32 + k4*4);
        unsigned v0 = Wm2p[k4*4+0][u4], v1 = Wm2p[k4*4+1][u4];
        unsigned v2 = Wm2p[k4*4+2][u4], v3 = Wm2p[k4*4+3][u4];
        acc2 += (v2f){lo4.x, hi4.x} * bp2(v0);
        acc2 += (v2f){lo4.y, hi4.y} * bp2(v1);
        acc2 += (v2f){lo4.z, hi4.z} * bp2(v2);
        acc2 += (v2f){lo4.w, hi4.w} * bp2(v3);
      }
      hbuf[p4][u4] = fmaxf(acc2[0] + acc2[1], 0.f);
    }
    __syncthreads();
  }
}

// ==================== mono fallback: 128 blocks (R4 kernel, verified) ====================
__global__ __launch_bounds__(1024, 1) void decoder_kernel_mono(
    const float* __restrict__ last_pos, const float* __restrict__ last_pos_rel,
    const float* __restrict__ hh, const float* __restrict__ ch,
    const int*  __restrict__ eg,
    const float* __restrict__ W_se, const float* __restrict__ b_se,
    const float* __restrict__ Wih, const float* __restrict__ Whh,
    const float* __restrict__ bih, const float* __restrict__ bhh,
    const float* __restrict__ W_hp, const float* __restrict__ b_hp,
    const float* __restrict__ W_pse, const float* __restrict__ b_pse,
    const float* __restrict__ W1a, const float* __restrict__ W2a,
    const float* __restrict__ W1b, const float* __restrict__ W2b,
    const float* __restrict__ W_m1, const float* __restrict__ b_m1,
    const float* __restrict__ W_m2, const float* __restrict__ b_m2,
    float* __restrict__ out)
{
  const int tid   = threadIdx.x;
  const int scn   = blockIdx.x;
  const int lane  = tid & 31;
  const int grp32 = tid >> 5;

  __shared__ __align__(16) float uni[4864];
  __shared__ __align__(16) unsigned W1p[2][16][GH];
  __shared__ __align__(16) float W2l[2][GH][GO];
  __shared__ __align__(16) float Wp1[2][2][GH];
  __shared__ __align__(16) float c1l[2][GH];
  __shared__ __align__(16) float hbuf[NP][HD];
  __shared__ __align__(16) float h2buf[NP][36];
  __shared__ __align__(16) float GS[2][5][GH];
  __shared__ __align__(16) float phbuf[NP][16];
  __shared__ __align__(16) unsigned Wm1p[48][32];
  __shared__ __align__(16) unsigned Wm2p[32][32];
  __shared__ float lpbuf[NP][2], rpbuf[NP][2], Whp[HD][2];
  __shared__ float bm1l[MD], bm2l[HD], bhp2[2];
  __shared__ unsigned bm[2][NP];
  __shared__ float invn[2][NP];
  __shared__ int gl[NP];

  const int myrow = tid & 127;
  const int pq4   = tid >> 7;
  float wrow[HD];
  #pragma unroll
  for (int c = 0; c < HD/4; c++) {
    float4 w = *(const float4*)(Whh + myrow*HD + c*4);
    wrow[c*4+0]=w.x; wrow[c*4+1]=w.y; wrow[c*4+2]=w.z; wrow[c*4+3]=w.w;
  }
  float wf0 = 0.f, wf1 = 0.f, bfr = bih[myrow] + bhh[myrow];
  #pragma unroll
  for (int e = 0; e < ED; e++) {
    float wv = Wih[myrow*ED + e];
    wf0 = fmaf(W_se[e],    wv, wf0);
    wf1 = fmaf(W_se[ED+e], wv, wf1);
    bfr = fmaf(b_se[e],    wv, bfr);
  }
  float creg = ch[(scn*NP + grp32)*HD + lane];
  hbuf[grp32][lane] = hh[(scn*NP + grp32)*HD + lane];

  if (tid < NP) {
    int gi = eg[scn*NP + tid];
    gl[tid] = gi;
    unsigned sm = 0;
    for (int j = 0; j < NP; j++) {
      int gj = eg[scn*NP + j];
      bool sj = (j == tid) || (gi == gj && gi != 0);
      sm |= ((unsigned)sj) << j;
    }
    unsigned dm = (~sm) | (1u << tid);
    bm[0][tid] = sm; bm[1][tid] = dm;
    invn[0][tid] = 1.0f/(float)__popc(sm);
    invn[1][tid] = 1.0f/(float)__popc(dm);
  }
  if (tid < 64) {
    int p = tid >> 1, k = tid & 1;
    lpbuf[p][k] = last_pos[(scn*NP+p)*2+k];
    rpbuf[p][k] = last_pos_rel[(scn*NP+p)*2+k];
    Whp[p][k]   = W_hp[tid];
    bm1l[tid]   = b_m1[tid];
  }
  if (tid < 32) bm2l[tid] = b_m2[tid];
  if (tid < 2)  bhp2[tid] = b_hp[tid];
  if (tid < 2*GH) {
    int m = tid / GH, d = tid % GH;
    const float* W1 = m ? W1b : W1a;
    float s0 = 0.f, s1 = 0.f, sc1 = 0.f;
    for (int e = 0; e < ED; e++) {
      float w = W1[e*GH + d];
      s0 += W_pse[e]*w; s1 += W_pse[ED+e]*w; sc1 += b_pse[e]*w;
    }
    Wp1[m][0][d] = s0; Wp1[m][1][d] = s1; c1l[m][d] = sc1;
  }
  {
    int u = tid;
    if (u < 2*GH*GO) {
      int m = u/(GH*GO), rest = u%(GH*GO);
      W2l[m][rest/GO][rest%GO] = (m ? W2b : W2a)[rest];
    }
    if (tid < 128) {
      int u2 = tid + 1024;
      int m = u2/(GH*GO), rest = u2%(GH*GO);
      W2l[m][rest/GO][rest%GO] = (m ? W2b : W2a)[rest];
    }
  }
  #pragma unroll
  for (int r = 0; r < 3; r++) {
    int u = tid + 1024*r;
    if (u < 2304) {
      int m = u/1152, rest = u%1152, k2 = rest/GH, d = rest%GH;
      const float* W1 = m ? W1b : W1a;
      W1p[m][k2][d] = rne16(W1[(ED+2*k2)*GH + d]) | (rne16(W1[(ED+2*k2+1)*GH + d]) << 16);
    }
  }
  #pragma unroll
  for (int r = 0; r < 2; r++) {
    int u = tid + 1024*r;
    if (u < 1536) {
      int k = u >> 5, uu = u & 31;
      Wm1p[k][uu] = rne16(W_m1[k*MD + uu]) | (rne16(W_m1[k*MD + 32 + uu]) << 16);
    }
  }
  {
    int k = tid >> 5, uu = tid & 31;
    Wm2p[k][uu] = rne16(W_m2[k*HD + uu]) | (rne16(W_m2[(k+32)*HD + uu]) << 16);
  }
  __syncthreads();

  for (int t = 0; t < TT; t++) {
    {
      float rG[4];
      #pragma unroll
      for (int pp2 = 0; pp2 < 4; pp2++) {
        int p = pq4*4 + pp2;
        float acc = fmaf(rpbuf[p][0], wf0, fmaf(rpbuf[p][1], wf1, bfr));
        #pragma unroll
        for (int c = 0; c < 8; c++) {
          float4 h4 = *(const float4*)&hbuf[p][c*4];
          acc = fmaf(h4.x, wrow[c*4+0], acc);
          acc = fmaf(h4.y, wrow[c*4+1], acc);
          acc = fmaf(h4.z, wrow[c*4+2], acc);
          acc = fmaf(h4.w, wrow[c*4+3], acc);
        }
        rG[pp2] = acc;
      }
      #pragma unroll
      for (int pp2 = 0; pp2 < 4; pp2++) uni[(pq4*4+pp2)*128 + myrow] = rG[pp2];
    }
    __syncthreads();
    {
      int p = grp32, n = lane;
      float gi_ = uni[p*128 + n];
      float gf_ = uni[p*128 + 32 + n];
      float gg_ = uni[p*128 + 64 + n];
      float go_ = uni[p*128 + 96 + n];
      float c2 = sigm(gf_)*creg + sigm(gi_)*tanhfast(gg_);
      creg = c2;
      float h2 = sigm(go_)*tanhfast(c2);
      h2buf[p][n] = h2;
      float r0 = h2 * Whp[n][0];
      float r1 = h2 * Whp[n][1];
      #pragma unroll
      for (int off = 1; off < 32; off <<= 1) {
        r0 += __shfl_xor(r0, off, 32);
        r1 += __shfl_xor(r1, off, 32);
      }
      r0 += bhp2[0]; r1 += bhp2[1];
      if (n == 0) {
        out[t*NB*2 + (scn*NP+p)*2 + 0] = r0;
        out[t*NB*2 + (scn*NP+p)*2 + 1] = r1;
        rpbuf[p][0] = r0;  rpbuf[p][1] = r1;
        lpbuf[p][0] += r0; lpbuf[p][1] += r1;
      }
    }
    __syncthreads();
    {
      const int j = lane;
      float lpj0 = lpbuf[j][0], lpj1 = lpbuf[j][1];
      float h2row[HD];
      #pragma unroll
      for (int c = 0; c < 8; c++) {
        float4 v = *(const float4*)&h2buf[j][c*4];
        h2row[c*4+0]=v.x; h2row[c*4+1]=v.y; h2row[c*4+2]=v.z; h2row[c*4+3]=v.w;
      }
      #pragma unroll
      for (int r = 0; r < 5; r++) {
        int rest = grp32 + 32*r;
        if (rest < 144) {
          int m = rest >= 72 ? 1 : 0;
          int d = rest - 72*m;
          float pp_ = fmaf(lpj0, Wp1[m][0][d], lpj1*Wp1[m][1][d]);
          float av = pp_;
          #pragma unroll
          for (int k2 = 0; k2 < 16; k2++) {
            unsigned v = W1p[m][k2][d];
            av = fmaf(h2row[2*k2], lo16(v), av);
            av = fmaf(h2row[2*k2+1], hi16(v), av);
          }
          uni[m*2432 + j*76 + d] = av;
          int gj = gl[j];
          float tot = av;
          float s1 = (gj==1)?av:0.f, s2=(gj==2)?av:0.f, s3=(gj==3)?av:0.f, s4=(gj==4)?av:0.f;
          #pragma unroll
          for (int off = 1; off < 32; off <<= 1) {
            tot += __shfl_xor(tot, off, 32);
            s1 += __shfl_xor(s1, off, 32);
            s2 += __shfl_xor(s2, off, 32);
            s3 += __shfl_xor(s3, off, 32);
            s4 += __shfl_xor(s4, off, 32);
          }
          if (j < 5) {
            float v2;
            if (m == 0) v2 = (j==0)?tot:((j==1)?s1:((j==2)?s2:((j==3)?s3:s4)));
            else        v2 = (j==0)?tot:((j==1)?tot-s1:((j==2)?tot-s2:((j==3)?tot-s3:tot-s4)));
            GS[m][j][d] = v2;
          }
        }
      }
    }
    __syncthreads();
    {
      const int j   = lane;
      const int m   = tid >> 9;
      const int sub = (tid >> 5) & 15;
      const float* am = uni + m*2432;
      int   I2[2] = {sub, sub + 16};
      const float *P0[2], *P1[2];
      float C0[2], C1[2], NL0[2], NL1[2];
      bool  MIJ[2], DIAG[2];
      v2f qv[2][4];
      #pragma unroll
      for (int r = 0; r < 2; r++) {
        int i = I2[r];
        unsigned bmv = bm[m][i];
        bool mij = (bmv >> j) & 1u;
        bool diag = (j == i);
        int gi = gl[i];
        float in_ = invn[m][i];
        const float *p0, *p1; float c0, c1c;
        if (diag) {
          if (m == 0) { p0 = gi ? &GS[0][gi][0] : (am + i*76); c0 = in_; p1 = am + i*76; c1c = 0.f; }
          else        { p0 = &GS[1][gi][0];                    c0 = in_; p1 = am + i*76; c1c = gi ? in_ : 0.f; }
        } else if (mij) { p0 = am + j*76; c0 = 0.5f; p1 = am + i*76; c1c = 0.5f; }
        else            { p0 = am + j*76; c0 = 1.0f; p1 = am + j*76; c1c = 0.f; }
        P0[r]=p0; P1[r]=p1; C0[r]=c0; C1[r]=c1c; MIJ[r]=mij; DIAG[r]=diag;
        NL0[r] = -lpbuf[i][0]; NL1[r] = -lpbuf[i][1];
        #pragma unroll
        for (int h = 0; h < 4; h++) qv[r][h] = (v2f){0.f, 0.f};
      }
      for (int d4 = 0; d4 < GH/4; d4++) {
        float4 c14 = *(const float4*)&c1l[m][d4*4];
        float4 w04 = *(const float4*)&Wp1[m][0][d4*4];
        float4 w14 = *(const float4*)&Wp1[m][1][d4*4];
        float4 vaS = *(const float4*)(am + j*76 + d4*4);
        float4 va0 = vaS, va1 = vaS;
        if (DIAG[0]) va0 = *(const float4*)(P0[0] + d4*4);
        if (DIAG[1]) va1 = *(const float4*)(P0[1] + d4*4);
        float4 vb0 = *(const float4*)(P1[0] + d4*4);
        float4 vb1 = *(const float4*)(P1[1] + d4*4);
        float e0x = fmaf(NL1[0], w14.x, fmaf(NL0[0], w04.x, c14.x));
        float e0y = fmaf(NL1[0], w14.y, fmaf(NL0[0], w04.y, c14.y));
        float e0z = fmaf(NL1[0], w14.z, fmaf(NL0[0], w04.z, c14.z));
        float e0w = fmaf(NL1[0], w14.w, fmaf(NL0[0], w04.w, c14.w));
        float e1x = fmaf(NL1[1], w14.x, fmaf(NL0[1], w04.x, c14.x));
        float e1y = fmaf(NL1[1], w14.y, fmaf(NL0[1], w04.y, c14.y));
        float e1z = fmaf(NL1[1], w14.z, fmaf(NL0[1], w04.z, c14.z));
        float e1w = fmaf(NL1[1], w14.w, fmaf(NL0[1], w04.w, c14.w));
        float tv0[4], tv1[4];
        tv0[0] = fmaxf(fmaf(C0[0], va0.x, fmaf(C1[0], vb0.x, e0x)), 0.f);
        tv0[1] = fmaxf(fmaf(C0[0], va0.y, fmaf(C1[0], vb0.y, e0y)), 0.f);
        tv0[2] = fmaxf(fmaf(C0[0], va0.z, fmaf(C1[0], vb0.z, e0z)), 0.f);
        tv0[3] = fmaxf(fmaf(C0[0], va0.w, fmaf(C1[0], vb0.w, e0w)), 0.f);
        tv1[0] = fmaxf(fmaf(C0[1], va1.x, fmaf(C1[1], vb1.x, e1x)), 0.f);
        tv1[1] = fmaxf(fmaf(C0[1], va1.y, fmaf(C1[1], vb1.y, e1y)), 0.f);
        tv1[2] = fmaxf(fmaf(C0[1], va1.z, fmaf(C1[1], vb1.z, e1z)), 0.f);
        tv1[3] = fmaxf(fmaf(C0[1], va1.w, fmaf(C1[1], vb1.w, e1w)), 0.f);
        #pragma unroll
        for (int k = 0; k < 4; k++) {
          const v2f* w2p = (const v2f*)&W2l[m][d4*4+k][0];
          v2f wA = w2p[0], wB = w2p[1], wC = w2p[2], wD = w2p[3];
          v2f t0 = {tv0[k], tv0[k]};
          qv[0][0] += t0*wA; qv[0][1] += t0*wB; qv[0][2] += t0*wC; qv[0][3] += t0*wD;
          v2f t1 = {tv1[k], tv1[k]};
          qv[1][0] += t1*wA; qv[1][1] += t1*wB; qv[1][2] += t1*wC; qv[1][3] += t1*wD;
        }
      }
      #pragma unroll
      for (int r = 0; r < 2; r++) {
        float q[8];
        #pragma unroll
        for (int h = 0; h < 4; h++) { q[2*h] = qv[r][h][0]; q[2*h+1] = qv[r][h][1]; }
        float sq[8];
        #pragma unroll
        for (int o = 0; o < 8; o++) sq[o] = MIJ[r] ? q[o] : 0.f;
        #pragma unroll
        for (int off = 1; off < 32; off <<= 1) {
          #pragma unroll
          for (int o = 0; o < 8; o++) sq[o] += __shfl_xor(sq[o], off, 32);
        }
        float qd[8];
        #pragma unroll
        for (int o = 0; o < 8; o++) qd[o] = __shfl(q[o], I2[r], 32);
        float in_ = invn[m][I2[r]];
        float F[8];
        if (DIAG[r]) {
          #pragma unroll
          for (int o = 0; o < 8; o++) F[o] = fmaxf(sq[o]*in_, 0.f);
        } else {
          float scl = MIJ[r] ? 0.5f : 1.0f;
          #pragma unroll
          for (int o = 0; o < 8; o++)
            F[o] = fmaxf((q[o] + (MIJ[r] ? qd[o] : 0.f))*scl, 0.f);
        }
        #pragma unroll
        for (int off = 1; off < 32; off <<= 1) {
          #pragma unroll
          for (int o = 0; o < 8; o++) F[o] = fmaxf(F[o], __shfl_xor(F[o], off, 32));
        }
        if (j == 0) {
          #pragma unroll
          for (int o = 0; o < 8; o++) phbuf[I2[r]][m*GO + o] = F[o];
        }
      }
    }
    __syncthreads();
    {
      int p = grp32, u = lane;
      float in48[48];
      #pragma unroll
      for (int c = 0; c < 8; c++) {
        float4 v = *(const float4*)&h2buf[p][c*4];
        in48[c*4+0]=v.x; in48[c*4+1]=v.y; in48[c*4+2]=v.z; in48[c*4+3]=v.w;
      }
      #pragma unroll
      for (int c = 0; c < 4; c++) {
        float4 v = *(const float4*)&phbuf[p][c*4];
        in48[32+c*4+0]=v.x; in48[32+c*4+1]=v.y; in48[32+c*4+2]=v.z; in48[32+c*4+3]=v.w;
      }
      float m1lo = bm1l[u], m1hi = bm1l[32 + u];
      #pragma unroll
      for (int k = 0; k < 48; k++) {
        unsigned v = Wm1p[k][u];
        m1lo = fmaf(in48[k], lo16(v), m1lo);
        m1hi = fmaf(in48[k], hi16(v), m1hi);
      }
      m1lo = fmaxf(m1lo, 0.f); m1hi = fmaxf(m1hi, 0.f);
      float acc = bm2l[u];
      #pragma unroll
      for (int k = 0; k < 32; k++) {
        unsigned v = Wm2p[k][u];
        acc = fmaf(__shfl(m1lo, k, 32), lo16(v), acc);
        acc = fmaf(__shfl(m1hi, k, 32), hi16(v), acc);
      }
      hbuf[p][u] = fmaxf(acc, 0.f);
    }
    __syncthreads();
  }
}

extern "C" void kernel_launch(void* const* d_in, const int* in_sizes, int n_in,
                              void* d_out, int out_size, void* d_ws, size_t ws_size,
                              hipStream_t stream) {
  (void)in_sizes; (void)n_in; (void)out_size;
  const float* last_pos     = (const float*)d_in[0];
  const float* last_pos_rel = (const float*)d_in[1];
  const float* hh           = (const float*)d_in[2];
  const float* ch           = (const float*)d_in[3];
  const int*  eg            = (const int*) d_in[5];
  const float* W_se  = (const float*)d_in[6];
  const float* b_se  = (const float*)d_in[7];
  const float* Wih   = (const float*)d_in[8];
  const float* Whh   = (const float*)d_in[9];
  const float* bih   = (const float*)d_in[10];
  const float* bhh   = (const float*)d_in[11];
  const float* W_hp  = (const float*)d_in[12];
  const float* b_hp  = (const float*)d_in[13];
  const float* W_pse = (const float*)d_in[14];
  const float* b_pse = (const float*)d_in[15];
  const float* W1a   = (const float*)d_in[16];
  const float* W2a   = (const float*)d_in[17];
  const float* W1b   = (const float*)d_in[18];
  const float* W2b   = (const float*)d_in[19];
  const float* W_m1  = (const float*)d_in[20];
  const float* b_m1  = (const float*)d_in[21];
  const float* W_m2  = (const float*)d_in[22];
  const float* b_m2  = (const float*)d_in[23];
  float* out = (float*)d_out;

  if (ws_size >= (size_t)WS_NEED) {
    decoder_kernel_split<<<2*NS, 1024, 0, stream>>>(
        last_pos, last_pos_rel, hh, ch, eg,
        W_se, b_se, Wih, Whh, bih, bhh, W_hp, b_hp, W_pse, b_pse,
        W1a, W2a, W1b, W2b, W_m1, b_m1, W_m2, b_m2, out, (float*)d_ws);
  } else {
    decoder_kernel_mono<<<NS, 1024, 0, stream>>>(
        last_pos, last_pos_rel, hh, ch, eg,
        W_se, b_se, Wih, Whh, bih, bhh, W_hp, b_hp, W_pse, b_pse,
        W1a, W2a, W1b, W2b, W_m1, b_m1, W_m2, b_m2, out);
  }
}